// Round 1
// baseline (1000.803 us; speedup 1.0000x reference)
//
#include <hip/hip_runtime.h>
#include <math.h>

// ---- problem constants ----
#define BB 16
#define CIN 256
#define MM 4096      // H*W
#define HIDC 256
#define NQ 300
#define NHH 4
#define HDD 16

// ---- output offsets (floats) ----
#define OFF_BOXES  0
#define OFF_SCORES 19200
#define OFF_CLS    24000
#define OFF_MAPS   408000
#define OFF_DIV    20068800
#define OFF_SF     20068801

// ---- workspace offsets (floats) ----
#define WS_COMB 0
#define WS_KEYS 16777216          // 16*256*4096
#define WS_T    20971520          // + 16*64*4096
#define WS_NORM 22200320          // + 16*300*256
#define WS_ACC  22205120          // + 4800

__global__ void zero_kernel(float* p){ p[0] = 0.f; }

// comb rows 128..255 = position encoding (batch-independent, replicated)
__global__ __launch_bounds__(256) void pos_fill_kernel(const float* __restrict__ pos_w,
                                                       const float* __restrict__ pos_b,
                                                       float* __restrict__ comb){
  int idx = blockIdx.x * 256 + threadIdx.x;      // c*4096 + m, c in 0..127
  int c = idx >> 12;
  int m = idx & 4095;
  int row = m >> 6, col = m & 63;
  float y = -1.f + 2.f * (float)row / 63.f;
  float x = -1.f + 2.f * (float)col / 63.f;
  float v = pos_w[c*2] * y + pos_w[c*2+1] * x + pos_b[c];
  #pragma unroll
  for (int b = 0; b < BB; b++)
    comb[((size_t)(b*HIDC + 128 + c))*MM + m] = v;
}

// comb rows 0..127 = relu(bn(fp_w[0:128] @ x + fp_b))
__global__ __launch_bounds__(256) void comb_gemm_kernel(const float* __restrict__ x,
    const float* __restrict__ fp_w, const float* __restrict__ fp_b,
    const float* __restrict__ bn_g, const float* __restrict__ bn_b,
    const float* __restrict__ bn_m, const float* __restrict__ bn_v,
    float* __restrict__ comb){
  int b = blockIdx.z;
  int row0 = blockIdx.y * 64;
  int col0 = blockIdx.x * 64;
  const float* xb = x + (size_t)b * CIN * MM;
  float* cb = comb + (size_t)b * HIDC * MM;
  __shared__ float as[16][68];
  __shared__ float bs[16][64];
  int tx = threadIdx.x, ty = threadIdx.y;
  int tid = ty * 16 + tx;
  float acc[4][4] = {};
  for (int k0 = 0; k0 < CIN; k0 += 16){
    {
      int i = tid >> 2, kk4 = (tid & 3) * 4;
      float4 av = *(const float4*)&fp_w[(size_t)(row0 + i) * CIN + k0 + kk4];
      as[kk4+0][i] = av.x; as[kk4+1][i] = av.y; as[kk4+2][i] = av.z; as[kk4+3][i] = av.w;
    }
    {
      int kk = tid >> 4, j = (tid & 15) * 4;
      *(float4*)&bs[kk][j] = *(const float4*)&xb[(size_t)(k0 + kk) * MM + col0 + j];
    }
    __syncthreads();
    #pragma unroll
    for (int kk = 0; kk < 16; kk++){
      float4 a4 = *(const float4*)&as[kk][ty*4];
      float4 b4 = *(const float4*)&bs[kk][tx*4];
      acc[0][0] += a4.x*b4.x; acc[0][1] += a4.x*b4.y; acc[0][2] += a4.x*b4.z; acc[0][3] += a4.x*b4.w;
      acc[1][0] += a4.y*b4.x; acc[1][1] += a4.y*b4.y; acc[1][2] += a4.y*b4.z; acc[1][3] += a4.y*b4.w;
      acc[2][0] += a4.z*b4.x; acc[2][1] += a4.z*b4.y; acc[2][2] += a4.z*b4.z; acc[2][3] += a4.z*b4.w;
      acc[3][0] += a4.w*b4.x; acc[3][1] += a4.w*b4.y; acc[3][2] += a4.w*b4.z; acc[3][3] += a4.w*b4.w;
    }
    __syncthreads();
  }
  #pragma unroll
  for (int ii = 0; ii < 4; ii++){
    int r = row0 + ty*4 + ii;
    float sc = rsqrtf(bn_v[r] + 1e-5f);
    float bias = fp_b[r], mu = bn_m[r], g = bn_g[r], bt = bn_b[r];
    float4 o;
    o.x = fmaxf((acc[ii][0] + bias - mu) * sc * g + bt, 0.f);
    o.y = fmaxf((acc[ii][1] + bias - mu) * sc * g + bt, 0.f);
    o.z = fmaxf((acc[ii][2] + bias - mu) * sc * g + bt, 0.f);
    o.w = fmaxf((acc[ii][3] + bias - mu) * sc * g + bt, 0.f);
    *(float4*)&cb[(size_t)r * MM + col0 + tx*4] = o;
  }
}

// keys = key_w(64x256) @ comb[b](256x4096) + key_b
__global__ __launch_bounds__(256) void keys_gemm_kernel(const float* __restrict__ comb,
    const float* __restrict__ key_w, const float* __restrict__ key_b,
    float* __restrict__ keys){
  int b = blockIdx.z;
  int col0 = blockIdx.x * 64;
  const float* cb = comb + (size_t)b * HIDC * MM;
  float* kb = keys + (size_t)b * 64 * MM;
  __shared__ float as[16][68];
  __shared__ float bs[16][64];
  int tx = threadIdx.x, ty = threadIdx.y;
  int tid = ty * 16 + tx;
  float acc[4][4] = {};
  for (int k0 = 0; k0 < HIDC; k0 += 16){
    {
      int i = tid >> 2, kk4 = (tid & 3) * 4;
      float4 av = *(const float4*)&key_w[(size_t)i * HIDC + k0 + kk4];
      as[kk4+0][i] = av.x; as[kk4+1][i] = av.y; as[kk4+2][i] = av.z; as[kk4+3][i] = av.w;
    }
    {
      int kk = tid >> 4, j = (tid & 15) * 4;
      *(float4*)&bs[kk][j] = *(const float4*)&cb[(size_t)(k0 + kk) * MM + col0 + j];
    }
    __syncthreads();
    #pragma unroll
    for (int kk = 0; kk < 16; kk++){
      float4 a4 = *(const float4*)&as[kk][ty*4];
      float4 b4 = *(const float4*)&bs[kk][tx*4];
      acc[0][0] += a4.x*b4.x; acc[0][1] += a4.x*b4.y; acc[0][2] += a4.x*b4.z; acc[0][3] += a4.x*b4.w;
      acc[1][0] += a4.y*b4.x; acc[1][1] += a4.y*b4.y; acc[1][2] += a4.y*b4.z; acc[1][3] += a4.y*b4.w;
      acc[2][0] += a4.z*b4.x; acc[2][1] += a4.z*b4.y; acc[2][2] += a4.z*b4.z; acc[2][3] += a4.z*b4.w;
      acc[3][0] += a4.w*b4.x; acc[3][1] += a4.w*b4.y; acc[3][2] += a4.w*b4.z; acc[3][3] += a4.w*b4.w;
    }
    __syncthreads();
  }
  #pragma unroll
  for (int ii = 0; ii < 4; ii++){
    int r = ty*4 + ii;
    float kbias = key_b[r];
    float4 o;
    o.x = acc[ii][0] + kbias; o.y = acc[ii][1] + kbias;
    o.z = acc[ii][2] + kbias; o.w = acc[ii][3] + kbias;
    *(float4*)&kb[(size_t)r * MM + col0 + tx*4] = o;
  }
}

// exp(q.k) for 4 consecutive m, accumulated scaled into o
__device__ __forceinline__ void dot16_exp4(const float* qp, const float4* kf, float4& o, float scale){
  float l0 = 0.f, l1 = 0.f, l2 = 0.f, l3 = 0.f;
  #pragma unroll
  for (int d4 = 0; d4 < 4; d4++){
    float4 q = ((const float4*)qp)[d4];
    float4 k0 = kf[d4*4+0], k1 = kf[d4*4+1], k2 = kf[d4*4+2], k3 = kf[d4*4+3];
    l0 += q.x*k0.x + q.y*k1.x + q.z*k2.x + q.w*k3.x;
    l1 += q.x*k0.y + q.y*k1.y + q.z*k2.y + q.w*k3.y;
    l2 += q.x*k0.z + q.y*k1.z + q.z*k2.z + q.w*k3.z;
    l3 += q.x*k0.w + q.y*k1.w + q.z*k2.w + q.w*k3.w;
  }
  o.x += __expf(l0) * scale;
  o.y += __expf(l1) * scale;
  o.z += __expf(l2) * scale;
  o.w += __expf(l3) * scale;
}

#define NT 10   // n-rows per block
// logits -> softmax(over m) -> head-mean; writes attn into maps; also per-row L2 norms.
// Logits are tiny (weights ~N(0,0.02^2)) so softmax without max-subtraction is exact-safe.
__global__ __launch_bounds__(256) void attn_kernel(const float* __restrict__ ss,
    const float* __restrict__ keys, float* __restrict__ attn_out, float* __restrict__ norms){
  int b = blockIdx.y;
  int n0 = blockIdx.x * NT;
  int tid = threadIdx.x;
  int w = tid >> 6, lane = tid & 63;
  __shared__ float qs[NT][NHH][HDD];
  __shared__ float sums[NT][NHH];
  __shared__ float invs[NT][NHH];
  __shared__ float norms_s[NHH][NT];
  for (int i = tid; i < NT*64; i += 256){
    int n = i >> 6, o = i & 63;
    qs[n][o >> 4][o & 15] = ss[(size_t)(n0 + n)*64 + o] * 0.25f;  // fold 1/sqrt(HD)
  }
  __syncthreads();
  const float* kb = keys + (size_t)b * 64 * MM;
  // ---- pass 1: wave w = head w; sum of exp per (n,h) ----
  float acc[NT];
  #pragma unroll
  for (int n = 0; n < NT; n++) acc[n] = 0.f;
  {
    int h = w;
    for (int g = lane; g < 1024; g += 64){
      float4 kf[16];
      #pragma unroll
      for (int d = 0; d < 16; d++)
        kf[d] = *(const float4*)&kb[(size_t)(h*16 + d)*MM + g*4];
      #pragma unroll
      for (int n = 0; n < NT; n++){
        float4 o = make_float4(0.f,0.f,0.f,0.f);
        dot16_exp4(&qs[n][h][0], kf, o, 1.f);
        acc[n] += o.x + o.y + o.z + o.w;
      }
    }
  }
  #pragma unroll
  for (int n = 0; n < NT; n++){
    float v = acc[n];
    #pragma unroll
    for (int off = 32; off >= 1; off >>= 1) v += __shfl_xor(v, off);
    if (lane == 0) sums[n][w] = v;
  }
  __syncthreads();
  for (int i = tid; i < NT*NHH; i += 256)
    invs[i / NHH][i % NHH] = 0.25f / sums[i / NHH][i % NHH];
  __syncthreads();
  // ---- pass 2: wave w handles m-quarter; combine heads, write attn, accumulate norms ----
  float normacc[NT];
  #pragma unroll
  for (int n = 0; n < NT; n++) normacc[n] = 0.f;
  float* ab = attn_out + ((size_t)b * NQ + n0) * MM;
  #pragma unroll
  for (int nc = 0; nc < NT; nc += 5){
    for (int g = w*256 + lane; g < (w+1)*256; g += 64){
      float4 o[5];
      #pragma unroll
      for (int j = 0; j < 5; j++) o[j] = make_float4(0.f,0.f,0.f,0.f);
      #pragma unroll
      for (int h = 0; h < 4; h++){
        float4 kf[16];
        #pragma unroll
        for (int d = 0; d < 16; d++)
          kf[d] = *(const float4*)&kb[(size_t)(h*16 + d)*MM + g*4];
        #pragma unroll
        for (int j = 0; j < 5; j++)
          dot16_exp4(&qs[nc + j][h][0], kf, o[j], invs[nc + j][h]);
      }
      #pragma unroll
      for (int j = 0; j < 5; j++){
        *(float4*)&ab[(size_t)(nc + j)*MM + g*4] = o[j];
        normacc[nc + j] += o[j].x*o[j].x + o[j].y*o[j].y + o[j].z*o[j].z + o[j].w*o[j].w;
      }
    }
  }
  #pragma unroll
  for (int n = 0; n < NT; n++){
    float v = normacc[n];
    #pragma unroll
    for (int off = 32; off >= 1; off >>= 1) v += __shfl_xor(v, off);
    if (lane == 0) norms_s[w][n] = v;
  }
  __syncthreads();
  if (tid < NT){
    float s = norms_s[0][tid] + norms_s[1][tid] + norms_s[2][tid] + norms_s[3][tid];
    norms[(size_t)b * NQ + n0 + tid] = sqrtf(s);
  }
}

// C[r,c] = sum_k A[r,k]*B[c,k] (+bias[c]) — both operands K-contiguous. 32x64 tile.
__global__ __launch_bounds__(256) void gemm_nt_kernel(
    const float* __restrict__ A, size_t strideA, int lda,
    const float* __restrict__ Bm, size_t strideB, int ldb,
    const float* __restrict__ bias,
    float* __restrict__ C, size_t strideC, int ldc,
    int Mr, int K){
  int bz = blockIdx.z;
  const float* Ab = A + (size_t)bz * strideA;
  const float* Bb = Bm + (size_t)bz * strideB;
  float* Cb = C + (size_t)bz * strideC;
  int row0 = blockIdx.y * 32, col0 = blockIdx.x * 64;
  int tx = threadIdx.x, ty = threadIdx.y;
  int tid = ty * 16 + tx;
  __shared__ float as[16][36];
  __shared__ float bs[16][68];
  float acc[2][4] = {};
  for (int k0 = 0; k0 < K; k0 += 16){
    if (tid < 128){
      int i = tid >> 2, kk4 = (tid & 3) * 4;
      int r = row0 + i;
      float4 av = make_float4(0.f,0.f,0.f,0.f);
      if (r < Mr) av = *(const float4*)&Ab[(size_t)r * lda + k0 + kk4];
      as[kk4+0][i] = av.x; as[kk4+1][i] = av.y; as[kk4+2][i] = av.z; as[kk4+3][i] = av.w;
    }
    {
      int j = tid >> 2, kk4 = (tid & 3) * 4;
      float4 bv = *(const float4*)&Bb[(size_t)(col0 + j) * ldb + k0 + kk4];
      bs[kk4+0][j] = bv.x; bs[kk4+1][j] = bv.y; bs[kk4+2][j] = bv.z; bs[kk4+3][j] = bv.w;
    }
    __syncthreads();
    #pragma unroll
    for (int kk = 0; kk < 16; kk++){
      float2 a2 = *(const float2*)&as[kk][ty*2];
      float4 b4 = *(const float4*)&bs[kk][tx*4];
      acc[0][0] += a2.x*b4.x; acc[0][1] += a2.x*b4.y; acc[0][2] += a2.x*b4.z; acc[0][3] += a2.x*b4.w;
      acc[1][0] += a2.y*b4.x; acc[1][1] += a2.y*b4.y; acc[1][2] += a2.y*b4.z; acc[1][3] += a2.y*b4.w;
    }
    __syncthreads();
  }
  #pragma unroll
  for (int ii = 0; ii < 2; ii++){
    int r = row0 + ty*2 + ii;
    if (r >= Mr) continue;
    #pragma unroll
    for (int jj = 0; jj < 4; jj++){
      int c = col0 + tx*4 + jj;
      float v = acc[ii][jj];
      if (bias) v += bias[c];
      Cb[(size_t)r * ldc + c] = v;
    }
  }
}

// diversity: sum_m (sum_n attn[n,m]/||attn_n||)^2, atomically accumulated
__global__ __launch_bounds__(256) void simdiv_kernel(const float* __restrict__ attn,
    const float* __restrict__ norms, float* __restrict__ acc){
  int b = blockIdx.y;
  int m = blockIdx.x * 256 + threadIdx.x;
  __shared__ float inv_s[NQ];
  __shared__ float red[4];
  for (int i = threadIdx.x; i < NQ; i += 256)
    inv_s[i] = 1.f / fmaxf(norms[(size_t)b * NQ + i], 1e-12f);
  __syncthreads();
  const float* ab = attn + (size_t)b * NQ * MM;
  float S = 0.f;
  for (int n = 0; n < NQ; n++)
    S += ab[(size_t)n * MM + m] * inv_s[n];
  float p = S * S;
  #pragma unroll
  for (int off = 32; off >= 1; off >>= 1) p += __shfl_xor(p, off);
  int w = threadIdx.x >> 6, lane = threadIdx.x & 63;
  if (lane == 0) red[w] = p;
  __syncthreads();
  if (threadIdx.x == 0) atomicAdd(acc, red[0] + red[1] + red[2] + red[3]);
}

__global__ void finalize_kernel(const float* __restrict__ acc, float* __restrict__ out_div){
  out_div[0] = (acc[0] - (float)(BB * NQ)) / (float)(NQ * (NQ - 1)) * 0.1f;
}

// fused MLP heads + cls. 4 waves/block, 5 rows/wave, 20 rows/block.
__global__ __launch_bounds__(256) void heads_kernel(const float* __restrict__ sf,
    const float* __restrict__ bb1_w, const float* __restrict__ bb1_b,
    const float* __restrict__ bbg,  const float* __restrict__ bbb,
    const float* __restrict__ bb2_w, const float* __restrict__ bb2_b,
    const float* __restrict__ bb3_w, const float* __restrict__ bb3_b,
    const float* __restrict__ ch1_w, const float* __restrict__ ch1_b,
    const float* __restrict__ chg,  const float* __restrict__ chb,
    const float* __restrict__ ch2_w, const float* __restrict__ ch2_b,
    const float* __restrict__ ch3_w, const float* __restrict__ ch3_b,
    const float* __restrict__ ctp_w, const float* __restrict__ ctp_b,
    float* __restrict__ boxes, float* __restrict__ scores, float* __restrict__ cls){
  int b = blockIdx.y;
  int n0 = blockIdx.x * 20;
  int tid = threadIdx.x;
  int w = tid >> 6, lane = tid & 63;
  __shared__ float sf_s[20][256];
  __shared__ float z1_s[20][256];
  __shared__ float z2_s[20][128];
  for (int i = tid; i < 20*256; i += 256)
    sf_s[i >> 8][i & 255] = sf[((size_t)b * NQ + n0 + (i >> 8)) * 256 + (i & 255)];
  __syncthreads();
  int r0 = w * 5;

  for (int headi = 0; headi < 2; headi++){
    const float* W1 = headi ? ch1_w : bb1_w;
    const float* B1 = headi ? ch1_b : bb1_b;
    const float* G  = headi ? chg  : bbg;
    const float* Bt = headi ? chb  : bbb;
    const float* W2 = headi ? ch2_w : bb2_w;
    const float* B2 = headi ? ch2_b : bb2_b;
    // z1 = W1 @ sf_row
    float a1[4][5] = {};
    for (int k = 0; k < 256; k += 4){
      float4 s[5];
      #pragma unroll
      for (int r = 0; r < 5; r++) s[r] = *(const float4*)&sf_s[r0 + r][k];
      #pragma unroll
      for (int j = 0; j < 4; j++){
        float4 wv = *(const float4*)&W1[(size_t)(lane + 64*j) * 256 + k];
        #pragma unroll
        for (int r = 0; r < 5; r++)
          a1[j][r] += wv.x*s[r].x + wv.y*s[r].y + wv.z*s[r].z + wv.w*s[r].w;
      }
    }
    float b10 = B1[lane], b11 = B1[lane+64], b12 = B1[lane+128], b13 = B1[lane+192];
    float g0 = G[lane],  g1 = G[lane+64],  g2 = G[lane+128],  g3 = G[lane+192];
    float t0 = Bt[lane], t1 = Bt[lane+64], t2 = Bt[lane+128], t3 = Bt[lane+192];
    #pragma unroll
    for (int r = 0; r < 5; r++){
      float v0 = a1[0][r] + b10, v1 = a1[1][r] + b11, v2 = a1[2][r] + b12, v3 = a1[3][r] + b13;
      float s = v0 + v1 + v2 + v3;
      #pragma unroll
      for (int off = 32; off >= 1; off >>= 1) s += __shfl_xor(s, off);
      float mean = s * (1.f/256.f);
      float d0 = v0 - mean, d1 = v1 - mean, d2 = v2 - mean, d3 = v3 - mean;
      float sq = d0*d0 + d1*d1 + d2*d2 + d3*d3;
      #pragma unroll
      for (int off = 32; off >= 1; off >>= 1) sq += __shfl_xor(sq, off);
      float inv = rsqrtf(sq * (1.f/256.f) + 1e-5f);
      z1_s[r0+r][lane]      = fmaxf(d0*inv*g0 + t0, 0.f);
      z1_s[r0+r][lane+64]   = fmaxf(d1*inv*g1 + t1, 0.f);
      z1_s[r0+r][lane+128]  = fmaxf(d2*inv*g2 + t2, 0.f);
      z1_s[r0+r][lane+192]  = fmaxf(d3*inv*g3 + t3, 0.f);
    }
    // z2 = relu(W2 @ z1)
    float a2[2][5] = {};
    for (int k = 0; k < 256; k += 4){
      float4 z[5];
      #pragma unroll
      for (int r = 0; r < 5; r++) z[r] = *(const float4*)&z1_s[r0 + r][k];
      #pragma unroll
      for (int j = 0; j < 2; j++){
        float4 wv = *(const float4*)&W2[(size_t)(lane + 64*j) * 256 + k];
        #pragma unroll
        for (int r = 0; r < 5; r++)
          a2[j][r] += wv.x*z[r].x + wv.y*z[r].y + wv.z*z[r].z + wv.w*z[r].w;
      }
    }
    #pragma unroll
    for (int j = 0; j < 2; j++){
      float bb_ = B2[lane + 64*j];
      #pragma unroll
      for (int r = 0; r < 5; r++)
        z2_s[r0+r][lane + 64*j] = fmaxf(a2[j][r] + bb_, 0.f);
    }
    if (headi == 0){
      if (lane < 20){
        int r = lane >> 2, o = lane & 3;
        float d = 0.f;
        for (int k = 0; k < 128; k += 4){
          float4 wv = *(const float4*)&bb3_w[o*128 + k];
          float4 z  = *(const float4*)&z2_s[r0 + r][k];
          d += wv.x*z.x + wv.y*z.y + wv.z*z.z + wv.w*z.w;
        }
        boxes[((size_t)b * NQ + n0 + r0 + r) * 4 + o] = d + bb3_b[o];
      }
    } else {
      if (lane < 5){
        int r = lane;
        float d = 0.f;
        for (int k = 0; k < 128; k += 4){
          float4 wv = *(const float4*)&ch3_w[k];
          float4 z  = *(const float4*)&z2_s[r0 + r][k];
          d += wv.x*z.x + wv.y*z.y + wv.z*z.z + wv.w*z.w;
        }
        float sv = d + ch3_b[0];
        scores[(size_t)b * NQ + n0 + r0 + r] = 1.f / (1.f + __expf(-sv));
      }
    }
  }
  // cls = ctp_w @ sf + ctp_b : 5 rows x 80 dims = 400 dots
  for (int it = 0; it < 7; it++){
    int idx = lane + 64*it;
    if (idx < 400){
      int r = idx / 80, o = idx % 80;
      float d = 0.f;
      for (int k = 0; k < 256; k += 4){
        float4 wv = *(const float4*)&ctp_w[(size_t)o*256 + k];
        float4 s  = *(const float4*)&sf_s[r0 + r][k];
        d += wv.x*s.x + wv.y*s.y + wv.z*s.z + wv.w*s.w;
      }
      cls[((size_t)b * NQ + n0 + r0 + r) * 80 + o] = d + ctp_b[o];
    }
  }
}

extern "C" void kernel_launch(void* const* d_in, const int* in_sizes, int n_in,
                              void* d_out, int out_size, void* d_ws, size_t ws_size,
                              hipStream_t stream){
  const float* x      = (const float*)d_in[0];
  const float* ss     = (const float*)d_in[1];
  const float* pos_w  = (const float*)d_in[2];
  const float* pos_b  = (const float*)d_in[3];
  const float* fp_w   = (const float*)d_in[4];
  const float* fp_b   = (const float*)d_in[5];
  const float* bn_g   = (const float*)d_in[6];
  const float* bn_b   = (const float*)d_in[7];
  const float* bn_m   = (const float*)d_in[8];
  const float* bn_v   = (const float*)d_in[9];
  const float* key_w  = (const float*)d_in[10];
  const float* key_b  = (const float*)d_in[11];
  const float* val_w  = (const float*)d_in[12];
  const float* val_b  = (const float*)d_in[13];
  const float* ctp_w  = (const float*)d_in[14];
  const float* ctp_b  = (const float*)d_in[15];
  const float* bb1_w  = (const float*)d_in[16];
  const float* bb1_b  = (const float*)d_in[17];
  const float* bbln_g = (const float*)d_in[18];
  const float* bbln_b = (const float*)d_in[19];
  const float* bb2_w  = (const float*)d_in[20];
  const float* bb2_b  = (const float*)d_in[21];
  const float* bb3_w  = (const float*)d_in[22];
  const float* bb3_b  = (const float*)d_in[23];
  const float* ch1_w  = (const float*)d_in[24];
  const float* ch1_b  = (const float*)d_in[25];
  const float* chln_g = (const float*)d_in[26];
  const float* chln_b = (const float*)d_in[27];
  const float* ch2_w  = (const float*)d_in[28];
  const float* ch2_b  = (const float*)d_in[29];
  const float* ch3_w  = (const float*)d_in[30];
  const float* ch3_b  = (const float*)d_in[31];

  float* out    = (float*)d_out;
  float* boxes  = out + OFF_BOXES;
  float* scores = out + OFF_SCORES;
  float* cls    = out + OFF_CLS;
  float* maps   = out + OFF_MAPS;
  float* divp   = out + OFF_DIV;
  float* sfout  = out + OFF_SF;

  float* ws    = (float*)d_ws;
  float* comb  = ws + WS_COMB;
  float* keys  = ws + WS_KEYS;
  float* tbuf  = ws + WS_T;
  float* norms = ws + WS_NORM;
  float* dacc  = ws + WS_ACC;

  zero_kernel<<<1, 1, 0, stream>>>(dacc);
  pos_fill_kernel<<<2048, 256, 0, stream>>>(pos_w, pos_b, comb);
  comb_gemm_kernel<<<dim3(64,2,16), dim3(16,16), 0, stream>>>(x, fp_w, fp_b, bn_g, bn_b, bn_m, bn_v, comb);
  keys_gemm_kernel<<<dim3(64,1,16), dim3(16,16), 0, stream>>>(comb, key_w, key_b, keys);
  attn_kernel<<<dim3(NQ/NT,16), 256, 0, stream>>>(ss, keys, maps, norms);
  // t = attn @ comb^T  (B,300,256)
  gemm_nt_kernel<<<dim3(4,10,16), dim3(16,16), 0, stream>>>(
      maps, (size_t)NQ*MM, MM, comb, (size_t)HIDC*MM, MM, nullptr,
      tbuf, (size_t)NQ*HIDC, HIDC, NQ, MM);
  // sf = t @ val_w^T + val_b  (written straight into d_out; sum(attn)==1 makes this exact)
  gemm_nt_kernel<<<dim3(4,10,16), dim3(16,16), 0, stream>>>(
      tbuf, (size_t)NQ*HIDC, HIDC, val_w, 0, HIDC, val_b,
      sfout, (size_t)NQ*HIDC, HIDC, NQ, HIDC);
  simdiv_kernel<<<dim3(16,16), 256, 0, stream>>>(maps, norms, dacc);
  finalize_kernel<<<1, 1, 0, stream>>>(dacc, divp);
  heads_kernel<<<dim3(15,16), 256, 0, stream>>>(sfout,
      bb1_w, bb1_b, bbln_g, bbln_b, bb2_w, bb2_b, bb3_w, bb3_b,
      ch1_w, ch1_b, chln_g, chln_b, ch2_w, ch2_b, ch3_w, ch3_b,
      ctp_w, ctp_b, boxes, scores, cls);
}

// Round 2
// 763.345 us; speedup vs baseline: 1.3111x; 1.3111x over previous
//
#include <hip/hip_runtime.h>
#include <math.h>

// ---- problem constants ----
#define BB 16
#define CIN 256
#define MM 4096      // H*W
#define HIDC 256
#define NQ 300
#define NHH 4
#define HDD 16

// ---- output offsets (floats) ----
#define OFF_BOXES  0
#define OFF_SCORES 19200
#define OFF_CLS    24000
#define OFF_MAPS   408000
#define OFF_DIV    20068800
#define OFF_SF     20068801

// ---- workspace offsets (in floats) ----
#define WS_COMB16  0            // 16*256*4096 ushort = 8388608 floats
#define WS_KEYS16  8388608      // 16*64*4096 ushort  = 2097152 floats
#define WS_ATTN16  10485760     // 16*300*4096 ushort = 9830400 floats
#define WS_T16     20316160     // 16*300*256 ushort  = 614400 floats
#define WS_VALW16  20930560     // 65536 ushort       = 32768 floats
#define WS_NORM    20963328     // 4800 floats
#define WS_ACC     20968128     // 1 float

typedef short short8 __attribute__((ext_vector_type(8)));
typedef float floatx4 __attribute__((ext_vector_type(4)));

__device__ __forceinline__ unsigned short f2bf(float f){
  unsigned int u = __float_as_uint(f);
  u = (u + 0x7FFFu + ((u >> 16) & 1u)) >> 16;
  return (unsigned short)u;
}
__device__ __forceinline__ float bf1(unsigned short u){
  return __uint_as_float((unsigned int)u << 16);
}
__device__ __forceinline__ float4 ld_bf4(const unsigned short* p){
  ushort4 u = *(const ushort4*)p;
  float4 f;
  f.x = bf1(u.x); f.y = bf1(u.y); f.z = bf1(u.z); f.w = bf1(u.w);
  return f;
}

__global__ void zero_kernel(float* p){ p[0] = 0.f; }

__global__ __launch_bounds__(256) void cast_bf16_kernel(const float* __restrict__ src,
                                                        unsigned short* __restrict__ dst, int n){
  int i = blockIdx.x * 256 + threadIdx.x;
  if (i < n) dst[i] = f2bf(src[i]);
}

// comb rows 128..255 = position encoding (batch-independent, replicated), bf16
__global__ __launch_bounds__(256) void pos_fill_kernel(const float* __restrict__ pos_w,
                                                       const float* __restrict__ pos_b,
                                                       unsigned short* __restrict__ comb16){
  int idx = blockIdx.x * 256 + threadIdx.x;      // c*4096 + m, c in 0..127
  int c = idx >> 12;
  int m = idx & 4095;
  int row = m >> 6, col = m & 63;
  float y = -1.f + 2.f * (float)row / 63.f;
  float x = -1.f + 2.f * (float)col / 63.f;
  unsigned short v = f2bf(pos_w[c*2] * y + pos_w[c*2+1] * x + pos_b[c]);
  #pragma unroll
  for (int b = 0; b < BB; b++)
    comb16[((size_t)(b*HIDC + 128 + c))*MM + m] = v;
}

// comb rows 0..127 = relu(bn(fp_w[0:128] @ x + fp_b)) -> bf16. 128x128 tile, 8x8/thread.
__global__ __launch_bounds__(256) void comb_gemm_kernel(const float* __restrict__ x,
    const float* __restrict__ fp_w, const float* __restrict__ fp_b,
    const float* __restrict__ bn_g, const float* __restrict__ bn_b,
    const float* __restrict__ bn_m, const float* __restrict__ bn_v,
    unsigned short* __restrict__ comb16){
  int b = blockIdx.z;
  int col0 = blockIdx.x * 128;
  const float* xb = x + (size_t)b * CIN * MM;
  unsigned short* cb = comb16 + (size_t)b * HIDC * MM;
  __shared__ float as[16][132];
  __shared__ float bs[16][128];
  int tx = threadIdx.x, ty = threadIdx.y;
  int tid = ty * 16 + tx;
  float acc[8][8] = {};
  for (int k0 = 0; k0 < CIN; k0 += 16){
    {
      int r = tid >> 1, kh = (tid & 1) * 8;
      float4 v0 = *(const float4*)&fp_w[(size_t)r * CIN + k0 + kh];
      float4 v1 = *(const float4*)&fp_w[(size_t)r * CIN + k0 + kh + 4];
      as[kh+0][r] = v0.x; as[kh+1][r] = v0.y; as[kh+2][r] = v0.z; as[kh+3][r] = v0.w;
      as[kh+4][r] = v1.x; as[kh+5][r] = v1.y; as[kh+6][r] = v1.z; as[kh+7][r] = v1.w;
    }
    {
      int kk = tid >> 4, j = (tid & 15) * 8;
      *(float4*)&bs[kk][j]     = *(const float4*)&xb[(size_t)(k0 + kk) * MM + col0 + j];
      *(float4*)&bs[kk][j + 4] = *(const float4*)&xb[(size_t)(k0 + kk) * MM + col0 + j + 4];
    }
    __syncthreads();
    #pragma unroll
    for (int kk = 0; kk < 16; kk++){
      float4 a0 = *(const float4*)&as[kk][ty*8];
      float4 a1 = *(const float4*)&as[kk][ty*8 + 4];
      float4 b0 = *(const float4*)&bs[kk][tx*8];
      float4 b1 = *(const float4*)&bs[kk][tx*8 + 4];
      float av[8] = {a0.x,a0.y,a0.z,a0.w,a1.x,a1.y,a1.z,a1.w};
      float bv[8] = {b0.x,b0.y,b0.z,b0.w,b1.x,b1.y,b1.z,b1.w};
      #pragma unroll
      for (int i = 0; i < 8; i++)
        #pragma unroll
        for (int j = 0; j < 8; j++)
          acc[i][j] += av[i] * bv[j];
    }
    __syncthreads();
  }
  #pragma unroll
  for (int i = 0; i < 8; i++){
    int r = ty*8 + i;
    float sc = rsqrtf(bn_v[r] + 1e-5f);
    float bias = fp_b[r], mu = bn_m[r], g = bn_g[r], bt = bn_b[r];
    ushort4 o0, o1;
    float v;
    v = fmaxf((acc[i][0] + bias - mu) * sc * g + bt, 0.f); o0.x = f2bf(v);
    v = fmaxf((acc[i][1] + bias - mu) * sc * g + bt, 0.f); o0.y = f2bf(v);
    v = fmaxf((acc[i][2] + bias - mu) * sc * g + bt, 0.f); o0.z = f2bf(v);
    v = fmaxf((acc[i][3] + bias - mu) * sc * g + bt, 0.f); o0.w = f2bf(v);
    v = fmaxf((acc[i][4] + bias - mu) * sc * g + bt, 0.f); o1.x = f2bf(v);
    v = fmaxf((acc[i][5] + bias - mu) * sc * g + bt, 0.f); o1.y = f2bf(v);
    v = fmaxf((acc[i][6] + bias - mu) * sc * g + bt, 0.f); o1.z = f2bf(v);
    v = fmaxf((acc[i][7] + bias - mu) * sc * g + bt, 0.f); o1.w = f2bf(v);
    *(ushort4*)&cb[(size_t)r * MM + col0 + tx*8]     = o0;
    *(ushort4*)&cb[(size_t)r * MM + col0 + tx*8 + 4] = o1;
  }
}

// keys = key_w(64x256) @ comb(256x4096) + key_b -> bf16. 64x128 tile, 4x8/thread.
__global__ __launch_bounds__(256) void keys_gemm_kernel(const unsigned short* __restrict__ comb16,
    const float* __restrict__ key_w, const float* __restrict__ key_b,
    unsigned short* __restrict__ keys16){
  int b = blockIdx.z;
  int col0 = blockIdx.x * 128;
  const unsigned short* cb = comb16 + (size_t)b * HIDC * MM;
  unsigned short* kb = keys16 + (size_t)b * 64 * MM;
  __shared__ float as[16][68];
  __shared__ float bs[16][132];
  int tx = threadIdx.x, ty = threadIdx.y;
  int tid = ty * 16 + tx;
  float acc[4][8] = {};
  for (int k0 = 0; k0 < HIDC; k0 += 16){
    {
      int r = tid >> 2, kh = (tid & 3) * 4;
      float4 v0 = *(const float4*)&key_w[(size_t)r * HIDC + k0 + kh];
      as[kh+0][r] = v0.x; as[kh+1][r] = v0.y; as[kh+2][r] = v0.z; as[kh+3][r] = v0.w;
    }
    {
      int kk = tid >> 4, j = (tid & 15) * 8;
      float4 f0 = ld_bf4(&cb[(size_t)(k0 + kk) * MM + col0 + j]);
      float4 f1 = ld_bf4(&cb[(size_t)(k0 + kk) * MM + col0 + j + 4]);
      *(float4*)&bs[kk][j]     = f0;
      *(float4*)&bs[kk][j + 4] = f1;
    }
    __syncthreads();
    #pragma unroll
    for (int kk = 0; kk < 16; kk++){
      float4 a0 = *(const float4*)&as[kk][ty*4];
      float4 b0 = *(const float4*)&bs[kk][tx*8];
      float4 b1 = *(const float4*)&bs[kk][tx*8 + 4];
      float av[4] = {a0.x,a0.y,a0.z,a0.w};
      float bv[8] = {b0.x,b0.y,b0.z,b0.w,b1.x,b1.y,b1.z,b1.w};
      #pragma unroll
      for (int i = 0; i < 4; i++)
        #pragma unroll
        for (int j = 0; j < 8; j++)
          acc[i][j] += av[i] * bv[j];
    }
    __syncthreads();
  }
  #pragma unroll
  for (int i = 0; i < 4; i++){
    int r = ty*4 + i;
    float kbias = key_b[r];
    ushort4 o0, o1;
    o0.x = f2bf(acc[i][0] + kbias); o0.y = f2bf(acc[i][1] + kbias);
    o0.z = f2bf(acc[i][2] + kbias); o0.w = f2bf(acc[i][3] + kbias);
    o1.x = f2bf(acc[i][4] + kbias); o1.y = f2bf(acc[i][5] + kbias);
    o1.z = f2bf(acc[i][6] + kbias); o1.w = f2bf(acc[i][7] + kbias);
    *(ushort4*)&kb[(size_t)r * MM + col0 + tx*8]     = o0;
    *(ushort4*)&kb[(size_t)r * MM + col0 + tx*8 + 4] = o1;
  }
}

// exp(q.k) for 4 consecutive m, accumulated scaled into o
__device__ __forceinline__ void dot16_exp4(const float* qp, const float4* kf, float4& o, float scale){
  float l0 = 0.f, l1 = 0.f, l2 = 0.f, l3 = 0.f;
  #pragma unroll
  for (int d4 = 0; d4 < 4; d4++){
    float4 q = ((const float4*)qp)[d4];
    float4 k0 = kf[d4*4+0], k1 = kf[d4*4+1], k2 = kf[d4*4+2], k3 = kf[d4*4+3];
    l0 += q.x*k0.x + q.y*k1.x + q.z*k2.x + q.w*k3.x;
    l1 += q.x*k0.y + q.y*k1.y + q.z*k2.y + q.w*k3.y;
    l2 += q.x*k0.z + q.y*k1.z + q.z*k2.z + q.w*k3.z;
    l3 += q.x*k0.w + q.y*k1.w + q.z*k2.w + q.w*k3.w;
  }
  o.x += __expf(l0) * scale;
  o.y += __expf(l1) * scale;
  o.z += __expf(l2) * scale;
  o.w += __expf(l3) * scale;
}

#define NT 10   // n-rows per block
// softmax(over m), head-mean; writes attn fp32 into maps + bf16 copy; per-row L2 norms.
__global__ __launch_bounds__(256) void attn_kernel(const float* __restrict__ ss,
    const unsigned short* __restrict__ keys16, float* __restrict__ attn_out,
    unsigned short* __restrict__ attn16, float* __restrict__ norms){
  int b = blockIdx.y;
  int n0 = blockIdx.x * NT;
  int tid = threadIdx.x;
  int w = tid >> 6, lane = tid & 63;
  __shared__ float qs[NT][NHH][HDD];
  __shared__ float sums[NT][NHH];
  __shared__ float invs[NT][NHH];
  __shared__ float norms_s[NHH][NT];
  for (int i = tid; i < NT*64; i += 256){
    int n = i >> 6, o = i & 63;
    qs[n][o >> 4][o & 15] = ss[(size_t)(n0 + n)*64 + o] * 0.25f;  // fold 1/sqrt(HD)
  }
  __syncthreads();
  const unsigned short* kb = keys16 + (size_t)b * 64 * MM;
  // ---- pass 1: wave w = head w; sum of exp per (n,h) ----
  float acc[NT];
  #pragma unroll
  for (int n = 0; n < NT; n++) acc[n] = 0.f;
  {
    int h = w;
    for (int g = lane; g < 1024; g += 64){
      float4 kf[16];
      #pragma unroll
      for (int d = 0; d < 16; d++)
        kf[d] = ld_bf4(&kb[(size_t)(h*16 + d)*MM + g*4]);
      #pragma unroll
      for (int n = 0; n < NT; n++){
        float4 o = make_float4(0.f,0.f,0.f,0.f);
        dot16_exp4(&qs[n][h][0], kf, o, 1.f);
        acc[n] += o.x + o.y + o.z + o.w;
      }
    }
  }
  #pragma unroll
  for (int n = 0; n < NT; n++){
    float v = acc[n];
    #pragma unroll
    for (int off = 32; off >= 1; off >>= 1) v += __shfl_xor(v, off);
    if (lane == 0) sums[n][w] = v;
  }
  __syncthreads();
  for (int i = tid; i < NT*NHH; i += 256)
    invs[i / NHH][i % NHH] = 0.25f / sums[i / NHH][i % NHH];
  __syncthreads();
  // ---- pass 2 ----
  float normacc[NT];
  #pragma unroll
  for (int n = 0; n < NT; n++) normacc[n] = 0.f;
  float* ab = attn_out + ((size_t)b * NQ + n0) * MM;
  unsigned short* ab16 = attn16 + ((size_t)b * NQ + n0) * MM;
  #pragma unroll
  for (int nc = 0; nc < NT; nc += 5){
    for (int g = w*256 + lane; g < (w+1)*256; g += 64){
      float4 o[5];
      #pragma unroll
      for (int j = 0; j < 5; j++) o[j] = make_float4(0.f,0.f,0.f,0.f);
      #pragma unroll
      for (int h = 0; h < 4; h++){
        float4 kf[16];
        #pragma unroll
        for (int d = 0; d < 16; d++)
          kf[d] = ld_bf4(&kb[(size_t)(h*16 + d)*MM + g*4]);
        #pragma unroll
        for (int j = 0; j < 5; j++)
          dot16_exp4(&qs[nc + j][h][0], kf, o[j], invs[nc + j][h]);
      }
      #pragma unroll
      for (int j = 0; j < 5; j++){
        *(float4*)&ab[(size_t)(nc + j)*MM + g*4] = o[j];
        ushort4 u;
        u.x = f2bf(o[j].x); u.y = f2bf(o[j].y); u.z = f2bf(o[j].z); u.w = f2bf(o[j].w);
        *(ushort4*)&ab16[(size_t)(nc + j)*MM + g*4] = u;
        normacc[nc + j] += o[j].x*o[j].x + o[j].y*o[j].y + o[j].z*o[j].z + o[j].w*o[j].w;
      }
    }
  }
  #pragma unroll
  for (int n = 0; n < NT; n++){
    float v = normacc[n];
    #pragma unroll
    for (int off = 32; off >= 1; off >>= 1) v += __shfl_xor(v, off);
    if (lane == 0) norms_s[w][n] = v;
  }
  __syncthreads();
  if (tid < NT){
    float s = norms_s[0][tid] + norms_s[1][tid] + norms_s[2][tid] + norms_s[3][tid];
    norms[(size_t)b * NQ + n0 + tid] = sqrtf(s);
  }
}

// C[M x 64*gridDim.x] = A[M x K] @ B[Nc x K]^T (+bias). bf16 NT MFMA, wave per 64x64 tile.
template<bool OUT_BF16>
__global__ __launch_bounds__(64) void mfma_nt_kernel(
    const unsigned short* __restrict__ A, size_t sA,
    const unsigned short* __restrict__ B, size_t sB,
    const float* __restrict__ bias,
    void* __restrict__ C, size_t sC, int ldc, int Mr, int K){
  int bz = blockIdx.z;
  const unsigned short* Ab = A + (size_t)bz * sA;
  const unsigned short* Bb = B + (size_t)bz * sB;
  int lane = threadIdx.x;
  int r16 = lane & 15;
  int ko  = (lane >> 4) * 8;
  const unsigned short* arow[4];
  const unsigned short* brow[4];
  #pragma unroll
  for (int i = 0; i < 4; i++){
    int m = blockIdx.y*64 + i*16 + r16;
    if (m > Mr - 1) m = Mr - 1;
    arow[i] = Ab + (size_t)m * K + ko;
    int n = blockIdx.x*64 + i*16 + r16;
    brow[i] = Bb + (size_t)n * K + ko;
  }
  floatx4 acc[4][4];
  #pragma unroll
  for (int i = 0; i < 4; i++)
    #pragma unroll
    for (int j = 0; j < 4; j++)
      acc[i][j] = (floatx4){0.f, 0.f, 0.f, 0.f};
  short8 a[4], bv[4], a2[4], b2[4];
  #pragma unroll
  for (int i = 0; i < 4; i++){
    a[i]  = *(const short8*)(arow[i]);
    bv[i] = *(const short8*)(brow[i]);
  }
  for (int k = 32; k < K; k += 32){
    #pragma unroll
    for (int i = 0; i < 4; i++){
      a2[i] = *(const short8*)(arow[i] + k);
      b2[i] = *(const short8*)(brow[i] + k);
    }
    #pragma unroll
    for (int i = 0; i < 4; i++)
      #pragma unroll
      for (int j = 0; j < 4; j++)
        acc[i][j] = __builtin_amdgcn_mfma_f32_16x16x32_bf16(a[i], bv[j], acc[i][j], 0, 0, 0);
    #pragma unroll
    for (int i = 0; i < 4; i++){ a[i] = a2[i]; bv[i] = b2[i]; }
  }
  #pragma unroll
  for (int i = 0; i < 4; i++)
    #pragma unroll
    for (int j = 0; j < 4; j++)
      acc[i][j] = __builtin_amdgcn_mfma_f32_16x16x32_bf16(a[i], bv[j], acc[i][j], 0, 0, 0);
  // epilogue: C/D layout col=lane&15, row=(lane>>4)*4+reg
  int cq = lane & 15, rq = (lane >> 4) * 4;
  #pragma unroll
  for (int j = 0; j < 4; j++){
    int cc = blockIdx.x*64 + j*16 + cq;
    float bv_ = bias ? bias[cc] : 0.f;
    #pragma unroll
    for (int i = 0; i < 4; i++){
      int rbase = blockIdx.y*64 + i*16 + rq;
      #pragma unroll
      for (int reg = 0; reg < 4; reg++){
        int rr = rbase + reg;
        if (rr < Mr){
          float v = acc[i][j][reg] + bv_;
          if (OUT_BF16)
            ((unsigned short*)C)[(size_t)bz * sC + (size_t)rr * ldc + cc] = f2bf(v);
          else
            ((float*)C)[(size_t)bz * sC + (size_t)rr * ldc + cc] = v;
        }
      }
    }
  }
}

// diversity: sum_m (sum_n attn[n,m]/||attn_n||)^2  (bf16 attn copy)
__global__ __launch_bounds__(256) void simdiv_kernel(const unsigned short* __restrict__ attn16,
    const float* __restrict__ norms, float* __restrict__ acc){
  int b = blockIdx.y;
  int m = blockIdx.x * 256 + threadIdx.x;
  __shared__ float inv_s[NQ];
  __shared__ float red[4];
  for (int i = threadIdx.x; i < NQ; i += 256)
    inv_s[i] = 1.f / fmaxf(norms[(size_t)b * NQ + i], 1e-12f);
  __syncthreads();
  const unsigned short* ab = attn16 + (size_t)b * NQ * MM;
  float S = 0.f;
  for (int n = 0; n < NQ; n++)
    S += bf1(ab[(size_t)n * MM + m]) * inv_s[n];
  float p = S * S;
  #pragma unroll
  for (int off = 32; off >= 1; off >>= 1) p += __shfl_xor(p, off);
  int w = threadIdx.x >> 6, lane = threadIdx.x & 63;
  if (lane == 0) red[w] = p;
  __syncthreads();
  if (threadIdx.x == 0) atomicAdd(acc, red[0] + red[1] + red[2] + red[3]);
}

__global__ void finalize_kernel(const float* __restrict__ acc, float* __restrict__ out_div){
  out_div[0] = (acc[0] - (float)(BB * NQ)) / (float)(NQ * (NQ - 1)) * 0.1f;
}

// fused MLP heads + cls. 4 waves/block, 5 rows/wave, 20 rows/block.
__global__ __launch_bounds__(256) void heads_kernel(const float* __restrict__ sf,
    const float* __restrict__ bb1_w, const float* __restrict__ bb1_b,
    const float* __restrict__ bbg,  const float* __restrict__ bbb,
    const float* __restrict__ bb2_w, const float* __restrict__ bb2_b,
    const float* __restrict__ bb3_w, const float* __restrict__ bb3_b,
    const float* __restrict__ ch1_w, const float* __restrict__ ch1_b,
    const float* __restrict__ chg,  const float* __restrict__ chb,
    const float* __restrict__ ch2_w, const float* __restrict__ ch2_b,
    const float* __restrict__ ch3_w, const float* __restrict__ ch3_b,
    const float* __restrict__ ctp_w, const float* __restrict__ ctp_b,
    float* __restrict__ boxes, float* __restrict__ scores, float* __restrict__ cls){
  int b = blockIdx.y;
  int n0 = blockIdx.x * 20;
  int tid = threadIdx.x;
  int w = tid >> 6, lane = tid & 63;
  __shared__ float sf_s[20][256];
  __shared__ float z1_s[20][256];
  __shared__ float z2_s[20][128];
  for (int i = tid; i < 20*256; i += 256)
    sf_s[i >> 8][i & 255] = sf[((size_t)b * NQ + n0 + (i >> 8)) * 256 + (i & 255)];
  __syncthreads();
  int r0 = w * 5;

  for (int headi = 0; headi < 2; headi++){
    const float* W1 = headi ? ch1_w : bb1_w;
    const float* B1 = headi ? ch1_b : bb1_b;
    const float* G  = headi ? chg  : bbg;
    const float* Bt = headi ? chb  : bbb;
    const float* W2 = headi ? ch2_w : bb2_w;
    const float* B2 = headi ? ch2_b : bb2_b;
    float a1[4][5] = {};
    for (int k = 0; k < 256; k += 4){
      float4 s[5];
      #pragma unroll
      for (int r = 0; r < 5; r++) s[r] = *(const float4*)&sf_s[r0 + r][k];
      #pragma unroll
      for (int j = 0; j < 4; j++){
        float4 wv = *(const float4*)&W1[(size_t)(lane + 64*j) * 256 + k];
        #pragma unroll
        for (int r = 0; r < 5; r++)
          a1[j][r] += wv.x*s[r].x + wv.y*s[r].y + wv.z*s[r].z + wv.w*s[r].w;
      }
    }
    float b10 = B1[lane], b11 = B1[lane+64], b12 = B1[lane+128], b13 = B1[lane+192];
    float g0 = G[lane],  g1 = G[lane+64],  g2 = G[lane+128],  g3 = G[lane+192];
    float t0 = Bt[lane], t1 = Bt[lane+64], t2 = Bt[lane+128], t3 = Bt[lane+192];
    #pragma unroll
    for (int r = 0; r < 5; r++){
      float v0 = a1[0][r] + b10, v1 = a1[1][r] + b11, v2 = a1[2][r] + b12, v3 = a1[3][r] + b13;
      float s = v0 + v1 + v2 + v3;
      #pragma unroll
      for (int off = 32; off >= 1; off >>= 1) s += __shfl_xor(s, off);
      float mean = s * (1.f/256.f);
      float d0 = v0 - mean, d1 = v1 - mean, d2 = v2 - mean, d3 = v3 - mean;
      float sq = d0*d0 + d1*d1 + d2*d2 + d3*d3;
      #pragma unroll
      for (int off = 32; off >= 1; off >>= 1) sq += __shfl_xor(sq, off);
      float inv = rsqrtf(sq * (1.f/256.f) + 1e-5f);
      z1_s[r0+r][lane]      = fmaxf(d0*inv*g0 + t0, 0.f);
      z1_s[r0+r][lane+64]   = fmaxf(d1*inv*g1 + t1, 0.f);
      z1_s[r0+r][lane+128]  = fmaxf(d2*inv*g2 + t2, 0.f);
      z1_s[r0+r][lane+192]  = fmaxf(d3*inv*g3 + t3, 0.f);
    }
    float a2[2][5] = {};
    for (int k = 0; k < 256; k += 4){
      float4 z[5];
      #pragma unroll
      for (int r = 0; r < 5; r++) z[r] = *(const float4*)&z1_s[r0 + r][k];
      #pragma unroll
      for (int j = 0; j < 2; j++){
        float4 wv = *(const float4*)&W2[(size_t)(lane + 64*j) * 256 + k];
        #pragma unroll
        for (int r = 0; r < 5; r++)
          a2[j][r] += wv.x*z[r].x + wv.y*z[r].y + wv.z*z[r].z + wv.w*z[r].w;
      }
    }
    #pragma unroll
    for (int j = 0; j < 2; j++){
      float bb_ = B2[lane + 64*j];
      #pragma unroll
      for (int r = 0; r < 5; r++)
        z2_s[r0+r][lane + 64*j] = fmaxf(a2[j][r] + bb_, 0.f);
    }
    if (headi == 0){
      if (lane < 20){
        int r = lane >> 2, o = lane & 3;
        float d = 0.f;
        for (int k = 0; k < 128; k += 4){
          float4 wv = *(const float4*)&bb3_w[o*128 + k];
          float4 z  = *(const float4*)&z2_s[r0 + r][k];
          d += wv.x*z.x + wv.y*z.y + wv.z*z.z + wv.w*z.w;
        }
        boxes[((size_t)b * NQ + n0 + r0 + r) * 4 + o] = d + bb3_b[o];
      }
    } else {
      if (lane < 5){
        int r = lane;
        float d = 0.f;
        for (int k = 0; k < 128; k += 4){
          float4 wv = *(const float4*)&ch3_w[k];
          float4 z  = *(const float4*)&z2_s[r0 + r][k];
          d += wv.x*z.x + wv.y*z.y + wv.z*z.z + wv.w*z.w;
        }
        float sv = d + ch3_b[0];
        scores[(size_t)b * NQ + n0 + r0 + r] = 1.f / (1.f + __expf(-sv));
      }
    }
  }
  for (int it = 0; it < 7; it++){
    int idx = lane + 64*it;
    if (idx < 400){
      int r = idx / 80, o = idx % 80;
      float d = 0.f;
      for (int k = 0; k < 256; k += 4){
        float4 wv = *(const float4*)&ctp_w[(size_t)o*256 + k];
        float4 s  = *(const float4*)&sf_s[r0 + r][k];
        d += wv.x*s.x + wv.y*s.y + wv.z*s.z + wv.w*s.w;
      }
      cls[((size_t)b * NQ + n0 + r0 + r) * 80 + o] = d + ctp_b[o];
    }
  }
}

extern "C" void kernel_launch(void* const* d_in, const int* in_sizes, int n_in,
                              void* d_out, int out_size, void* d_ws, size_t ws_size,
                              hipStream_t stream){
  const float* x      = (const float*)d_in[0];
  const float* ss     = (const float*)d_in[1];
  const float* pos_w  = (const float*)d_in[2];
  const float* pos_b  = (const float*)d_in[3];
  const float* fp_w   = (const float*)d_in[4];
  const float* fp_b   = (const float*)d_in[5];
  const float* bn_g   = (const float*)d_in[6];
  const float* bn_b   = (const float*)d_in[7];
  const float* bn_m   = (const float*)d_in[8];
  const float* bn_v   = (const float*)d_in[9];
  const float* key_w  = (const float*)d_in[10];
  const float* key_b  = (const float*)d_in[11];
  const float* val_w  = (const float*)d_in[12];
  const float* val_b  = (const float*)d_in[13];
  const float* ctp_w  = (const float*)d_in[14];
  const float* ctp_b  = (const float*)d_in[15];
  const float* bb1_w  = (const float*)d_in[16];
  const float* bb1_b  = (const float*)d_in[17];
  const float* bbln_g = (const float*)d_in[18];
  const float* bbln_b = (const float*)d_in[19];
  const float* bb2_w  = (const float*)d_in[20];
  const float* bb2_b  = (const float*)d_in[21];
  const float* bb3_w  = (const float*)d_in[22];
  const float* bb3_b  = (const float*)d_in[23];
  const float* ch1_w  = (const float*)d_in[24];
  const float* ch1_b  = (const float*)d_in[25];
  const float* chln_g = (const float*)d_in[26];
  const float* chln_b = (const float*)d_in[27];
  const float* ch2_w  = (const float*)d_in[28];
  const float* ch2_b  = (const float*)d_in[29];
  const float* ch3_w  = (const float*)d_in[30];
  const float* ch3_b  = (const float*)d_in[31];

  float* out    = (float*)d_out;
  float* boxes  = out + OFF_BOXES;
  float* scores = out + OFF_SCORES;
  float* cls    = out + OFF_CLS;
  float* maps   = out + OFF_MAPS;
  float* divp   = out + OFF_DIV;
  float* sfout  = out + OFF_SF;

  float* ws = (float*)d_ws;
  unsigned short* comb16 = (unsigned short*)(ws + WS_COMB16);
  unsigned short* keys16 = (unsigned short*)(ws + WS_KEYS16);
  unsigned short* attn16 = (unsigned short*)(ws + WS_ATTN16);
  unsigned short* t16    = (unsigned short*)(ws + WS_T16);
  unsigned short* valw16 = (unsigned short*)(ws + WS_VALW16);
  float* norms = ws + WS_NORM;
  float* dacc  = ws + WS_ACC;

  zero_kernel<<<1, 1, 0, stream>>>(dacc);
  cast_bf16_kernel<<<256, 256, 0, stream>>>(val_w, valw16, 65536);
  pos_fill_kernel<<<2048, 256, 0, stream>>>(pos_w, pos_b, comb16);
  comb_gemm_kernel<<<dim3(32,1,16), dim3(16,16), 0, stream>>>(x, fp_w, fp_b, bn_g, bn_b, bn_m, bn_v, comb16);
  keys_gemm_kernel<<<dim3(32,1,16), dim3(16,16), 0, stream>>>(comb16, key_w, key_b, keys16);
  attn_kernel<<<dim3(NQ/NT,16), 256, 0, stream>>>(ss, keys16, maps, attn16, norms);
  // t16 = attn @ comb^T   (B,300,256) bf16
  mfma_nt_kernel<true><<<dim3(4,5,16), 64, 0, stream>>>(
      attn16, (size_t)NQ*MM, comb16, (size_t)HIDC*MM, nullptr,
      (void*)t16, (size_t)NQ*HIDC, HIDC, NQ, MM);
  // sf = t @ val_w^T + val_b  (fp32, straight into d_out)
  mfma_nt_kernel<false><<<dim3(4,5,16), 64, 0, stream>>>(
      t16, (size_t)NQ*HIDC, valw16, 0, val_b,
      (void*)sfout, (size_t)NQ*HIDC, HIDC, NQ, HIDC);
  simdiv_kernel<<<dim3(16,16), 256, 0, stream>>>(attn16, norms, dacc);
  finalize_kernel<<<1, 1, 0, stream>>>(dacc, divp);
  heads_kernel<<<dim3(15,16), 256, 0, stream>>>(sfout,
      bb1_w, bb1_b, bbln_g, bbln_b, bb2_w, bb2_b, bb3_w, bb3_b,
      ch1_w, ch1_b, chln_g, chln_b, ch2_w, ch2_b, ch3_w, ch3_b,
      ctp_w, ctp_b, boxes, scores, cls);
}

// Round 3
// 655.084 us; speedup vs baseline: 1.5277x; 1.1653x over previous
//
#include <hip/hip_runtime.h>
#include <math.h>

// ---- problem constants ----
#define BB 16
#define CIN 256
#define MM 4096      // H*W
#define HIDC 256
#define NQ 300
#define NHH 4
#define HDD 16

// ---- output offsets (floats) ----
#define OFF_BOXES  0
#define OFF_SCORES 19200
#define OFF_CLS    24000
#define OFF_MAPS   408000
#define OFF_DIV    20068800
#define OFF_SF     20068801

// ---- workspace offsets (in floats) ----
#define WS_COMB16  0            // 16*256*4096 ushort = 8388608 floats
#define WS_KEYS16  8388608      // 16*64*4096 ushort  = 2097152 floats
#define WS_ATTN16  10485760     // 16*300*4096 ushort = 9830400 floats
#define WS_T32     20316160     // 16*300*256 fp32    = 1228800 floats
#define WS_T16     21544960     // 16*300*256 ushort  = 614400 floats
#define WS_VALW16  22159360     // 65536 ushort       = 32768 floats
#define WS_SUMS    22192128     // 16*4*300 fp32      = 19200 floats
#define WS_NORM    22211328     // 4800 floats
#define WS_ACC     22216128     // 1 float (+pad)
#define WS_P       22216192     // 16*4*300*4096 ushort = 39321600 floats
#define WS_TOTAL_P 61537792ull  // floats needed for stored-P path

typedef short short8 __attribute__((ext_vector_type(8)));
typedef float floatx4 __attribute__((ext_vector_type(4)));

__device__ __forceinline__ unsigned short f2bf(float f){
  unsigned int u = __float_as_uint(f);
  u = (u + 0x7FFFu + ((u >> 16) & 1u)) >> 16;
  return (unsigned short)u;
}
__device__ __forceinline__ float bf1(unsigned short u){
  return __uint_as_float((unsigned int)u << 16);
}
__device__ __forceinline__ float4 ld_bf4(const unsigned short* p){
  ushort4 u = *(const ushort4*)p;
  float4 f;
  f.x = bf1(u.x); f.y = bf1(u.y); f.z = bf1(u.z); f.w = bf1(u.w);
  return f;
}

__global__ void zero_kernel(float* p){ p[0] = 0.f; }

__global__ __launch_bounds__(256) void zero4_kernel(float4* __restrict__ p, int n4){
  int i = blockIdx.x * 256 + threadIdx.x;
  if (i < n4) p[i] = make_float4(0.f, 0.f, 0.f, 0.f);
}

__global__ __launch_bounds__(256) void cast_bf16_kernel(const float* __restrict__ src,
                                                        unsigned short* __restrict__ dst, int n){
  int i = blockIdx.x * 256 + threadIdx.x;
  if (i < n) dst[i] = f2bf(src[i]);
}

__global__ __launch_bounds__(256) void cast4_bf16_kernel(const float* __restrict__ src,
                                                         unsigned short* __restrict__ dst, int n4){
  int i = blockIdx.x * 256 + threadIdx.x;
  if (i < n4){
    float4 v = ((const float4*)src)[i];
    ushort4 u;
    u.x = f2bf(v.x); u.y = f2bf(v.y); u.z = f2bf(v.z); u.w = f2bf(v.w);
    ((ushort4*)dst)[i] = u;
  }
}

// comb rows 128..255 = position encoding (batch-independent, replicated), bf16
__global__ __launch_bounds__(256) void pos_fill_kernel(const float* __restrict__ pos_w,
                                                       const float* __restrict__ pos_b,
                                                       unsigned short* __restrict__ comb16){
  int idx = blockIdx.x * 256 + threadIdx.x;      // c*4096 + m, c in 0..127
  int c = idx >> 12;
  int m = idx & 4095;
  int row = m >> 6, col = m & 63;
  float y = -1.f + 2.f * (float)row / 63.f;
  float x = -1.f + 2.f * (float)col / 63.f;
  unsigned short v = f2bf(pos_w[c*2] * y + pos_w[c*2+1] * x + pos_b[c]);
  #pragma unroll
  for (int b = 0; b < BB; b++)
    comb16[((size_t)(b*HIDC + 128 + c))*MM + m] = v;
}

// comb rows 0..127 = relu(bn(fp_w[0:128] @ x + fp_b)) -> bf16. 128x128 tile, 8x8/thread.
__global__ __launch_bounds__(256) void comb_gemm_kernel(const float* __restrict__ x,
    const float* __restrict__ fp_w, const float* __restrict__ fp_b,
    const float* __restrict__ bn_g, const float* __restrict__ bn_b,
    const float* __restrict__ bn_m, const float* __restrict__ bn_v,
    unsigned short* __restrict__ comb16){
  int b = blockIdx.z;
  int col0 = blockIdx.x * 128;
  const float* xb = x + (size_t)b * CIN * MM;
  unsigned short* cb = comb16 + (size_t)b * HIDC * MM;
  __shared__ float as[16][132];
  __shared__ float bs[16][128];
  int tx = threadIdx.x, ty = threadIdx.y;
  int tid = ty * 16 + tx;
  float acc[8][8] = {};
  for (int k0 = 0; k0 < CIN; k0 += 16){
    {
      int r = tid >> 1, kh = (tid & 1) * 8;
      float4 v0 = *(const float4*)&fp_w[(size_t)r * CIN + k0 + kh];
      float4 v1 = *(const float4*)&fp_w[(size_t)r * CIN + k0 + kh + 4];
      as[kh+0][r] = v0.x; as[kh+1][r] = v0.y; as[kh+2][r] = v0.z; as[kh+3][r] = v0.w;
      as[kh+4][r] = v1.x; as[kh+5][r] = v1.y; as[kh+6][r] = v1.z; as[kh+7][r] = v1.w;
    }
    {
      int kk = tid >> 4, j = (tid & 15) * 8;
      *(float4*)&bs[kk][j]     = *(const float4*)&xb[(size_t)(k0 + kk) * MM + col0 + j];
      *(float4*)&bs[kk][j + 4] = *(const float4*)&xb[(size_t)(k0 + kk) * MM + col0 + j + 4];
    }
    __syncthreads();
    #pragma unroll
    for (int kk = 0; kk < 16; kk++){
      float4 a0 = *(const float4*)&as[kk][ty*8];
      float4 a1 = *(const float4*)&as[kk][ty*8 + 4];
      float4 b0 = *(const float4*)&bs[kk][tx*8];
      float4 b1 = *(const float4*)&bs[kk][tx*8 + 4];
      float av[8] = {a0.x,a0.y,a0.z,a0.w,a1.x,a1.y,a1.z,a1.w};
      float bv[8] = {b0.x,b0.y,b0.z,b0.w,b1.x,b1.y,b1.z,b1.w};
      #pragma unroll
      for (int i = 0; i < 8; i++)
        #pragma unroll
        for (int j = 0; j < 8; j++)
          acc[i][j] += av[i] * bv[j];
    }
    __syncthreads();
  }
  #pragma unroll
  for (int i = 0; i < 8; i++){
    int r = ty*8 + i;
    float sc = rsqrtf(bn_v[r] + 1e-5f);
    float bias = fp_b[r], mu = bn_m[r], g = bn_g[r], bt = bn_b[r];
    ushort4 o0, o1;
    float v;
    v = fmaxf((acc[i][0] + bias - mu) * sc * g + bt, 0.f); o0.x = f2bf(v);
    v = fmaxf((acc[i][1] + bias - mu) * sc * g + bt, 0.f); o0.y = f2bf(v);
    v = fmaxf((acc[i][2] + bias - mu) * sc * g + bt, 0.f); o0.z = f2bf(v);
    v = fmaxf((acc[i][3] + bias - mu) * sc * g + bt, 0.f); o0.w = f2bf(v);
    v = fmaxf((acc[i][4] + bias - mu) * sc * g + bt, 0.f); o1.x = f2bf(v);
    v = fmaxf((acc[i][5] + bias - mu) * sc * g + bt, 0.f); o1.y = f2bf(v);
    v = fmaxf((acc[i][6] + bias - mu) * sc * g + bt, 0.f); o1.z = f2bf(v);
    v = fmaxf((acc[i][7] + bias - mu) * sc * g + bt, 0.f); o1.w = f2bf(v);
    *(ushort4*)&cb[(size_t)r * MM + col0 + tx*8]     = o0;
    *(ushort4*)&cb[(size_t)r * MM + col0 + tx*8 + 4] = o1;
  }
}

// keys = key_w(64x256) @ comb(256x4096) + key_b -> bf16. 64x128 tile, 4x8/thread.
__global__ __launch_bounds__(256) void keys_gemm_kernel(const unsigned short* __restrict__ comb16,
    const float* __restrict__ key_w, const float* __restrict__ key_b,
    unsigned short* __restrict__ keys16){
  int b = blockIdx.z;
  int col0 = blockIdx.x * 128;
  const unsigned short* cb = comb16 + (size_t)b * HIDC * MM;
  unsigned short* kb = keys16 + (size_t)b * 64 * MM;
  __shared__ float as[16][68];
  __shared__ float bs[16][132];
  int tx = threadIdx.x, ty = threadIdx.y;
  int tid = ty * 16 + tx;
  float acc[4][8] = {};
  for (int k0 = 0; k0 < HIDC; k0 += 16){
    {
      int r = tid >> 2, kh = (tid & 3) * 4;
      float4 v0 = *(const float4*)&key_w[(size_t)r * HIDC + k0 + kh];
      as[kh+0][r] = v0.x; as[kh+1][r] = v0.y; as[kh+2][r] = v0.z; as[kh+3][r] = v0.w;
    }
    {
      int kk = tid >> 4, j = (tid & 15) * 8;
      float4 f0 = ld_bf4(&cb[(size_t)(k0 + kk) * MM + col0 + j]);
      float4 f1 = ld_bf4(&cb[(size_t)(k0 + kk) * MM + col0 + j + 4]);
      *(float4*)&bs[kk][j]     = f0;
      *(float4*)&bs[kk][j + 4] = f1;
    }
    __syncthreads();
    #pragma unroll
    for (int kk = 0; kk < 16; kk++){
      float4 a0 = *(const float4*)&as[kk][ty*4];
      float4 b0 = *(const float4*)&bs[kk][tx*8];
      float4 b1 = *(const float4*)&bs[kk][tx*8 + 4];
      float av[4] = {a0.x,a0.y,a0.z,a0.w};
      float bv[8] = {b0.x,b0.y,b0.z,b0.w,b1.x,b1.y,b1.z,b1.w};
      #pragma unroll
      for (int i = 0; i < 4; i++)
        #pragma unroll
        for (int j = 0; j < 8; j++)
          acc[i][j] += av[i] * bv[j];
    }
    __syncthreads();
  }
  #pragma unroll
  for (int i = 0; i < 4; i++){
    int r = ty*4 + i;
    float kbias = key_b[r];
    ushort4 o0, o1;
    o0.x = f2bf(acc[i][0] + kbias); o0.y = f2bf(acc[i][1] + kbias);
    o0.z = f2bf(acc[i][2] + kbias); o0.w = f2bf(acc[i][3] + kbias);
    o1.x = f2bf(acc[i][4] + kbias); o1.y = f2bf(acc[i][5] + kbias);
    o1.z = f2bf(acc[i][6] + kbias); o1.w = f2bf(acc[i][7] + kbias);
    *(ushort4*)&kb[(size_t)r * MM + col0 + tx*8]     = o0;
    *(ushort4*)&kb[(size_t)r * MM + col0 + tx*8 + 4] = o1;
  }
}

// exp(q.k) for 4 consecutive m, accumulated scaled into o
__device__ __forceinline__ void dot16_exp4(const float* qp, const float4* kf, float4& o, float scale){
  float l0 = 0.f, l1 = 0.f, l2 = 0.f, l3 = 0.f;
  #pragma unroll
  for (int d4 = 0; d4 < 4; d4++){
    float4 q = ((const float4*)qp)[d4];
    float4 k0 = kf[d4*4+0], k1 = kf[d4*4+1], k2 = kf[d4*4+2], k3 = kf[d4*4+3];
    l0 += q.x*k0.x + q.y*k1.x + q.z*k2.x + q.w*k3.x;
    l1 += q.x*k0.y + q.y*k1.y + q.z*k2.y + q.w*k3.y;
    l2 += q.x*k0.z + q.y*k1.z + q.z*k2.z + q.w*k3.z;
    l3 += q.x*k0.w + q.y*k1.w + q.z*k2.w + q.w*k3.w;
  }
  o.x += __expf(l0) * scale;
  o.y += __expf(l1) * scale;
  o.z += __expf(l2) * scale;
  o.w += __expf(l3) * scale;
}

// ======== stored-P attention path ========
// P[b][h][n][m] = exp(q.k/4) bf16 (single exp pass), row sums -> sums[b][h][n]
#define ET 10
__global__ __launch_bounds__(256) void expsum_kernel(const float* __restrict__ ss,
    const unsigned short* __restrict__ keys16,
    unsigned short* __restrict__ P, float* __restrict__ sums){
  int b = blockIdx.z, h = blockIdx.y, n0 = blockIdx.x * ET;
  int tid = threadIdx.x;
  int w = tid >> 6, lane = tid & 63;
  __shared__ float qs[ET][HDD];
  __shared__ float part[NHH][ET];
  if (tid < ET*HDD)
    qs[tid >> 4][tid & 15] = ss[(size_t)(n0 + (tid >> 4))*64 + h*16 + (tid & 15)] * 0.25f;
  __syncthreads();
  const unsigned short* kb = keys16 + ((size_t)b*64 + h*16)*MM;
  unsigned short* Pb = P + (((size_t)b*NHH + h)*NQ + n0)*MM;
  float acc[ET];
  #pragma unroll
  for (int n = 0; n < ET; n++) acc[n] = 0.f;
  for (int it = 0; it < 4; it++){
    int g = it*256 + tid;            // m-group (4 m each)
    float4 kf[16];
    #pragma unroll
    for (int d = 0; d < 16; d++)
      kf[d] = ld_bf4(&kb[(size_t)d*MM + g*4]);
    #pragma unroll
    for (int n = 0; n < ET; n++){
      float4 o = make_float4(0.f,0.f,0.f,0.f);
      dot16_exp4(&qs[n][0], kf, o, 1.f);
      ushort4 u;
      u.x = f2bf(o.x); u.y = f2bf(o.y); u.z = f2bf(o.z); u.w = f2bf(o.w);
      *(ushort4*)&Pb[(size_t)n*MM + g*4] = u;
      acc[n] += o.x + o.y + o.z + o.w;
    }
  }
  #pragma unroll
  for (int n = 0; n < ET; n++){
    float v = acc[n];
    #pragma unroll
    for (int off = 32; off >= 1; off >>= 1) v += __shfl_xor(v, off);
    if (lane == 0) part[w][n] = v;
  }
  __syncthreads();
  if (tid < ET)
    sums[((size_t)b*NHH + h)*NQ + n0 + tid] = part[0][tid] + part[1][tid] + part[2][tid] + part[3][tid];
}

// attn = 0.25 * sum_h P_h / S_h; writes maps fp32 + attn16 bf16 + per-row L2 norms.
#define CT 3
__global__ __launch_bounds__(256) void combine_kernel(const unsigned short* __restrict__ P,
    const float* __restrict__ sums, float* __restrict__ maps,
    unsigned short* __restrict__ attn16, float* __restrict__ norms){
  int b = blockIdx.y, n0 = blockIdx.x * CT;
  int tid = threadIdx.x;
  int w = tid >> 6, lane = tid & 63;
  __shared__ float inv_s[CT][NHH];
  __shared__ float part[NHH][CT];
  if (tid < CT*NHH){
    int n = tid >> 2, h = tid & 3;
    inv_s[n][h] = 0.25f / sums[((size_t)b*NHH + h)*NQ + n0 + n];
  }
  __syncthreads();
  const unsigned short* Pb = P + ((size_t)b*NHH*NQ + n0)*MM;
  float* mb = maps + ((size_t)b*NQ + n0)*MM;
  unsigned short* ab = attn16 + ((size_t)b*NQ + n0)*MM;
  float nacc[CT];
  #pragma unroll
  for (int n = 0; n < CT; n++) nacc[n] = 0.f;
  for (int it = 0; it < 4; it++){
    int g = it*256 + tid;
    #pragma unroll
    for (int n = 0; n < CT; n++){
      float4 o = make_float4(0.f,0.f,0.f,0.f);
      #pragma unroll
      for (int h = 0; h < NHH; h++){
        float4 p = ld_bf4(&Pb[((size_t)h*NQ + n)*MM + g*4]);
        float iv = inv_s[n][h];
        o.x += p.x*iv; o.y += p.y*iv; o.z += p.z*iv; o.w += p.w*iv;
      }
      *(float4*)&mb[(size_t)n*MM + g*4] = o;
      ushort4 u;
      u.x = f2bf(o.x); u.y = f2bf(o.y); u.z = f2bf(o.z); u.w = f2bf(o.w);
      *(ushort4*)&ab[(size_t)n*MM + g*4] = u;
      nacc[n] += o.x*o.x + o.y*o.y + o.z*o.z + o.w*o.w;
    }
  }
  #pragma unroll
  for (int n = 0; n < CT; n++){
    float v = nacc[n];
    #pragma unroll
    for (int off = 32; off >= 1; off >>= 1) v += __shfl_xor(v, off);
    if (lane == 0) part[w][n] = v;
  }
  __syncthreads();
  if (tid < CT)
    norms[(size_t)b*NQ + n0 + tid] = sqrtf(part[0][tid] + part[1][tid] + part[2][tid] + part[3][tid]);
}

// ======== fallback 2-pass attention (used if ws too small for P) ========
#define NT 10
__global__ __launch_bounds__(256) void attn_kernel(const float* __restrict__ ss,
    const unsigned short* __restrict__ keys16, float* __restrict__ attn_out,
    unsigned short* __restrict__ attn16, float* __restrict__ norms){
  int b = blockIdx.y;
  int n0 = blockIdx.x * NT;
  int tid = threadIdx.x;
  int w = tid >> 6, lane = tid & 63;
  __shared__ float qs[NT][NHH][HDD];
  __shared__ float sums[NT][NHH];
  __shared__ float invs[NT][NHH];
  __shared__ float norms_s[NHH][NT];
  for (int i = tid; i < NT*64; i += 256){
    int n = i >> 6, o = i & 63;
    qs[n][o >> 4][o & 15] = ss[(size_t)(n0 + n)*64 + o] * 0.25f;
  }
  __syncthreads();
  const unsigned short* kb = keys16 + (size_t)b * 64 * MM;
  float acc[NT];
  #pragma unroll
  for (int n = 0; n < NT; n++) acc[n] = 0.f;
  {
    int h = w;
    for (int g = lane; g < 1024; g += 64){
      float4 kf[16];
      #pragma unroll
      for (int d = 0; d < 16; d++)
        kf[d] = ld_bf4(&kb[(size_t)(h*16 + d)*MM + g*4]);
      #pragma unroll
      for (int n = 0; n < NT; n++){
        float4 o = make_float4(0.f,0.f,0.f,0.f);
        dot16_exp4(&qs[n][h][0], kf, o, 1.f);
        acc[n] += o.x + o.y + o.z + o.w;
      }
    }
  }
  #pragma unroll
  for (int n = 0; n < NT; n++){
    float v = acc[n];
    #pragma unroll
    for (int off = 32; off >= 1; off >>= 1) v += __shfl_xor(v, off);
    if (lane == 0) sums[n][w] = v;
  }
  __syncthreads();
  for (int i = tid; i < NT*NHH; i += 256)
    invs[i / NHH][i % NHH] = 0.25f / sums[i / NHH][i % NHH];
  __syncthreads();
  float normacc[NT];
  #pragma unroll
  for (int n = 0; n < NT; n++) normacc[n] = 0.f;
  float* ab = attn_out + ((size_t)b * NQ + n0) * MM;
  unsigned short* ab16 = attn16 + ((size_t)b * NQ + n0) * MM;
  #pragma unroll
  for (int nc = 0; nc < NT; nc += 5){
    for (int g = w*256 + lane; g < (w+1)*256; g += 64){
      float4 o[5];
      #pragma unroll
      for (int j = 0; j < 5; j++) o[j] = make_float4(0.f,0.f,0.f,0.f);
      #pragma unroll
      for (int h = 0; h < 4; h++){
        float4 kf[16];
        #pragma unroll
        for (int d = 0; d < 16; d++)
          kf[d] = ld_bf4(&kb[(size_t)(h*16 + d)*MM + g*4]);
        #pragma unroll
        for (int j = 0; j < 5; j++)
          dot16_exp4(&qs[nc + j][h][0], kf, o[j], invs[nc + j][h]);
      }
      #pragma unroll
      for (int j = 0; j < 5; j++){
        *(float4*)&ab[(size_t)(nc + j)*MM + g*4] = o[j];
        ushort4 u;
        u.x = f2bf(o[j].x); u.y = f2bf(o[j].y); u.z = f2bf(o[j].z); u.w = f2bf(o[j].w);
        *(ushort4*)&ab16[(size_t)(nc + j)*MM + g*4] = u;
        normacc[nc + j] += o[j].x*o[j].x + o[j].y*o[j].y + o[j].z*o[j].z + o[j].w*o[j].w;
      }
    }
  }
  #pragma unroll
  for (int n = 0; n < NT; n++){
    float v = normacc[n];
    #pragma unroll
    for (int off = 32; off >= 1; off >>= 1) v += __shfl_xor(v, off);
    if (lane == 0) norms_s[w][n] = v;
  }
  __syncthreads();
  if (tid < NT){
    float s = norms_s[0][tid] + norms_s[1][tid] + norms_s[2][tid] + norms_s[3][tid];
    norms[(size_t)b * NQ + n0 + tid] = sqrtf(s);
  }
}

// C = A @ B^T (+bias). bf16 NT MFMA, wave per 64x64 tile.
template<bool OUT_BF16>
__global__ __launch_bounds__(64) void mfma_nt_kernel(
    const unsigned short* __restrict__ A, size_t sA,
    const unsigned short* __restrict__ B, size_t sB,
    const float* __restrict__ bias,
    void* __restrict__ C, size_t sC, int ldc, int Mr, int K){
  int bz = blockIdx.z;
  const unsigned short* Ab = A + (size_t)bz * sA;
  const unsigned short* Bb = B + (size_t)bz * sB;
  int lane = threadIdx.x;
  int r16 = lane & 15;
  int ko  = (lane >> 4) * 8;
  const unsigned short* arow[4];
  const unsigned short* brow[4];
  #pragma unroll
  for (int i = 0; i < 4; i++){
    int m = blockIdx.y*64 + i*16 + r16;
    if (m > Mr - 1) m = Mr - 1;
    arow[i] = Ab + (size_t)m * K + ko;
    int n = blockIdx.x*64 + i*16 + r16;
    brow[i] = Bb + (size_t)n * K + ko;
  }
  floatx4 acc[4][4];
  #pragma unroll
  for (int i = 0; i < 4; i++)
    #pragma unroll
    for (int j = 0; j < 4; j++)
      acc[i][j] = (floatx4){0.f, 0.f, 0.f, 0.f};
  short8 a[4], bv[4], a2[4], b2[4];
  #pragma unroll
  for (int i = 0; i < 4; i++){
    a[i]  = *(const short8*)(arow[i]);
    bv[i] = *(const short8*)(brow[i]);
  }
  for (int k = 32; k < K; k += 32){
    #pragma unroll
    for (int i = 0; i < 4; i++){
      a2[i] = *(const short8*)(arow[i] + k);
      b2[i] = *(const short8*)(brow[i] + k);
    }
    #pragma unroll
    for (int i = 0; i < 4; i++)
      #pragma unroll
      for (int j = 0; j < 4; j++)
        acc[i][j] = __builtin_amdgcn_mfma_f32_16x16x32_bf16(a[i], bv[j], acc[i][j], 0, 0, 0);
    #pragma unroll
    for (int i = 0; i < 4; i++){ a[i] = a2[i]; bv[i] = b2[i]; }
  }
  #pragma unroll
  for (int i = 0; i < 4; i++)
    #pragma unroll
    for (int j = 0; j < 4; j++)
      acc[i][j] = __builtin_amdgcn_mfma_f32_16x16x32_bf16(a[i], bv[j], acc[i][j], 0, 0, 0);
  int cq = lane & 15, rq = (lane >> 4) * 4;
  #pragma unroll
  for (int j = 0; j < 4; j++){
    int cc = blockIdx.x*64 + j*16 + cq;
    float bv_ = bias ? bias[cc] : 0.f;
    #pragma unroll
    for (int i = 0; i < 4; i++){
      int rbase = blockIdx.y*64 + i*16 + rq;
      #pragma unroll
      for (int reg = 0; reg < 4; reg++){
        int rr = rbase + reg;
        if (rr < Mr){
          float v = acc[i][j][reg] + bv_;
          if (OUT_BF16)
            ((unsigned short*)C)[(size_t)bz * sC + (size_t)rr * ldc + cc] = f2bf(v);
          else
            ((float*)C)[(size_t)bz * sC + (size_t)rr * ldc + cc] = v;
        }
      }
    }
  }
}

// split-K variant: fp32 atomicAdd into pre-zeroed C
__global__ __launch_bounds__(64) void mfma_nt_splitk_kernel(
    const unsigned short* __restrict__ A, size_t sA,
    const unsigned short* __restrict__ B, size_t sB,
    float* __restrict__ C, size_t sC, int ldc, int Mr, int K, int kchunk){
  int nks = K / kchunk;
  int bz = blockIdx.z / nks;
  int kz = blockIdx.z % nks;
  const unsigned short* Ab = A + (size_t)bz * sA + (size_t)kz * kchunk;
  const unsigned short* Bb = B + (size_t)bz * sB + (size_t)kz * kchunk;
  int lane = threadIdx.x;
  int r16 = lane & 15;
  int ko  = (lane >> 4) * 8;
  const unsigned short* arow[4];
  const unsigned short* brow[4];
  #pragma unroll
  for (int i = 0; i < 4; i++){
    int m = blockIdx.y*64 + i*16 + r16;
    if (m > Mr - 1) m = Mr - 1;
    arow[i] = Ab + (size_t)m * K + ko;
    int n = blockIdx.x*64 + i*16 + r16;
    brow[i] = Bb + (size_t)n * K + ko;
  }
  floatx4 acc[4][4];
  #pragma unroll
  for (int i = 0; i < 4; i++)
    #pragma unroll
    for (int j = 0; j < 4; j++)
      acc[i][j] = (floatx4){0.f, 0.f, 0.f, 0.f};
  short8 a[4], bv[4], a2[4], b2[4];
  #pragma unroll
  for (int i = 0; i < 4; i++){
    a[i]  = *(const short8*)(arow[i]);
    bv[i] = *(const short8*)(brow[i]);
  }
  for (int k = 32; k < kchunk; k += 32){
    #pragma unroll
    for (int i = 0; i < 4; i++){
      a2[i] = *(const short8*)(arow[i] + k);
      b2[i] = *(const short8*)(brow[i] + k);
    }
    #pragma unroll
    for (int i = 0; i < 4; i++)
      #pragma unroll
      for (int j = 0; j < 4; j++)
        acc[i][j] = __builtin_amdgcn_mfma_f32_16x16x32_bf16(a[i], bv[j], acc[i][j], 0, 0, 0);
    #pragma unroll
    for (int i = 0; i < 4; i++){ a[i] = a2[i]; bv[i] = b2[i]; }
  }
  #pragma unroll
  for (int i = 0; i < 4; i++)
    #pragma unroll
    for (int j = 0; j < 4; j++)
      acc[i][j] = __builtin_amdgcn_mfma_f32_16x16x32_bf16(a[i], bv[j], acc[i][j], 0, 0, 0);
  int cq = lane & 15, rq = (lane >> 4) * 4;
  #pragma unroll
  for (int j = 0; j < 4; j++){
    int cc = blockIdx.x*64 + j*16 + cq;
    #pragma unroll
    for (int i = 0; i < 4; i++){
      int rbase = blockIdx.y*64 + i*16 + rq;
      #pragma unroll
      for (int reg = 0; reg < 4; reg++){
        int rr = rbase + reg;
        if (rr < Mr)
          atomicAdd(&C[(size_t)bz * sC + (size_t)rr * ldc + cc], acc[i][j][reg]);
      }
    }
  }
}

// diversity: sum_m (sum_n attn[n,m]/||attn_n||)^2  (bf16 attn copy)
__global__ __launch_bounds__(256) void simdiv_kernel(const unsigned short* __restrict__ attn16,
    const float* __restrict__ norms, float* __restrict__ acc){
  int b = blockIdx.y;
  int m = blockIdx.x * 256 + threadIdx.x;
  __shared__ float inv_s[NQ];
  __shared__ float red[4];
  for (int i = threadIdx.x; i < NQ; i += 256)
    inv_s[i] = 1.f / fmaxf(norms[(size_t)b * NQ + i], 1e-12f);
  __syncthreads();
  const unsigned short* ab = attn16 + (size_t)b * NQ * MM;
  float S = 0.f;
  for (int n = 0; n < NQ; n++)
    S += bf1(ab[(size_t)n * MM + m]) * inv_s[n];
  float p = S * S;
  #pragma unroll
  for (int off = 32; off >= 1; off >>= 1) p += __shfl_xor(p, off);
  int w = threadIdx.x >> 6, lane = threadIdx.x & 63;
  if (lane == 0) red[w] = p;
  __syncthreads();
  if (threadIdx.x == 0) atomicAdd(acc, red[0] + red[1] + red[2] + red[3]);
}

__global__ void finalize_kernel(const float* __restrict__ acc, float* __restrict__ out_div){
  out_div[0] = (acc[0] - (float)(BB * NQ)) / (float)(NQ * (NQ - 1)) * 0.1f;
}

// fused MLP heads + cls. 4 waves/block, 5 rows/wave, 20 rows/block.
__global__ __launch_bounds__(256) void heads_kernel(const float* __restrict__ sf,
    const float* __restrict__ bb1_w, const float* __restrict__ bb1_b,
    const float* __restrict__ bbg,  const float* __restrict__ bbb,
    const float* __restrict__ bb2_w, const float* __restrict__ bb2_b,
    const float* __restrict__ bb3_w, const float* __restrict__ bb3_b,
    const float* __restrict__ ch1_w, const float* __restrict__ ch1_b,
    const float* __restrict__ chg,  const float* __restrict__ chb,
    const float* __restrict__ ch2_w, const float* __restrict__ ch2_b,
    const float* __restrict__ ch3_w, const float* __restrict__ ch3_b,
    const float* __restrict__ ctp_w, const float* __restrict__ ctp_b,
    float* __restrict__ boxes, float* __restrict__ scores, float* __restrict__ cls){
  int b = blockIdx.y;
  int n0 = blockIdx.x * 20;
  int tid = threadIdx.x;
  int w = tid >> 6, lane = tid & 63;
  __shared__ float sf_s[20][256];
  __shared__ float z1_s[20][256];
  __shared__ float z2_s[20][128];
  for (int i = tid; i < 20*256; i += 256)
    sf_s[i >> 8][i & 255] = sf[((size_t)b * NQ + n0 + (i >> 8)) * 256 + (i & 255)];
  __syncthreads();
  int r0 = w * 5;

  for (int headi = 0; headi < 2; headi++){
    const float* W1 = headi ? ch1_w : bb1_w;
    const float* B1 = headi ? ch1_b : bb1_b;
    const float* G  = headi ? chg  : bbg;
    const float* Bt = headi ? chb  : bbb;
    const float* W2 = headi ? ch2_w : bb2_w;
    const float* B2 = headi ? ch2_b : bb2_b;
    float a1[4][5] = {};
    for (int k = 0; k < 256; k += 4){
      float4 s[5];
      #pragma unroll
      for (int r = 0; r < 5; r++) s[r] = *(const float4*)&sf_s[r0 + r][k];
      #pragma unroll
      for (int j = 0; j < 4; j++){
        float4 wv = *(const float4*)&W1[(size_t)(lane + 64*j) * 256 + k];
        #pragma unroll
        for (int r = 0; r < 5; r++)
          a1[j][r] += wv.x*s[r].x + wv.y*s[r].y + wv.z*s[r].z + wv.w*s[r].w;
      }
    }
    float b10 = B1[lane], b11 = B1[lane+64], b12 = B1[lane+128], b13 = B1[lane+192];
    float g0 = G[lane],  g1 = G[lane+64],  g2 = G[lane+128],  g3 = G[lane+192];
    float t0 = Bt[lane], t1 = Bt[lane+64], t2 = Bt[lane+128], t3 = Bt[lane+192];
    #pragma unroll
    for (int r = 0; r < 5; r++){
      float v0 = a1[0][r] + b10, v1 = a1[1][r] + b11, v2 = a1[2][r] + b12, v3 = a1[3][r] + b13;
      float s = v0 + v1 + v2 + v3;
      #pragma unroll
      for (int off = 32; off >= 1; off >>= 1) s += __shfl_xor(s, off);
      float mean = s * (1.f/256.f);
      float d0 = v0 - mean, d1 = v1 - mean, d2 = v2 - mean, d3 = v3 - mean;
      float sq = d0*d0 + d1*d1 + d2*d2 + d3*d3;
      #pragma unroll
      for (int off = 32; off >= 1; off >>= 1) sq += __shfl_xor(sq, off);
      float inv = rsqrtf(sq * (1.f/256.f) + 1e-5f);
      z1_s[r0+r][lane]      = fmaxf(d0*inv*g0 + t0, 0.f);
      z1_s[r0+r][lane+64]   = fmaxf(d1*inv*g1 + t1, 0.f);
      z1_s[r0+r][lane+128]  = fmaxf(d2*inv*g2 + t2, 0.f);
      z1_s[r0+r][lane+192]  = fmaxf(d3*inv*g3 + t3, 0.f);
    }
    float a2[2][5] = {};
    for (int k = 0; k < 256; k += 4){
      float4 z[5];
      #pragma unroll
      for (int r = 0; r < 5; r++) z[r] = *(const float4*)&z1_s[r0 + r][k];
      #pragma unroll
      for (int j = 0; j < 2; j++){
        float4 wv = *(const float4*)&W2[(size_t)(lane + 64*j) * 256 + k];
        #pragma unroll
        for (int r = 0; r < 5; r++)
          a2[j][r] += wv.x*z[r].x + wv.y*z[r].y + wv.z*z[r].z + wv.w*z[r].w;
      }
    }
    #pragma unroll
    for (int j = 0; j < 2; j++){
      float bb_ = B2[lane + 64*j];
      #pragma unroll
      for (int r = 0; r < 5; r++)
        z2_s[r0+r][lane + 64*j] = fmaxf(a2[j][r] + bb_, 0.f);
    }
    if (headi == 0){
      if (lane < 20){
        int r = lane >> 2, o = lane & 3;
        float d = 0.f;
        for (int k = 0; k < 128; k += 4){
          float4 wv = *(const float4*)&bb3_w[o*128 + k];
          float4 z  = *(const float4*)&z2_s[r0 + r][k];
          d += wv.x*z.x + wv.y*z.y + wv.z*z.z + wv.w*z.w;
        }
        boxes[((size_t)b * NQ + n0 + r0 + r) * 4 + o] = d + bb3_b[o];
      }
    } else {
      if (lane < 5){
        int r = lane;
        float d = 0.f;
        for (int k = 0; k < 128; k += 4){
          float4 wv = *(const float4*)&ch3_w[k];
          float4 z  = *(const float4*)&z2_s[r0 + r][k];
          d += wv.x*z.x + wv.y*z.y + wv.z*z.z + wv.w*z.w;
        }
        float sv = d + ch3_b[0];
        scores[(size_t)b * NQ + n0 + r0 + r] = 1.f / (1.f + __expf(-sv));
      }
    }
  }
  for (int it = 0; it < 7; it++){
    int idx = lane + 64*it;
    if (idx < 400){
      int r = idx / 80, o = idx % 80;
      float d = 0.f;
      for (int k = 0; k < 256; k += 4){
        float4 wv = *(const float4*)&ctp_w[(size_t)o*256 + k];
        float4 s  = *(const float4*)&sf_s[r0 + r][k];
        d += wv.x*s.x + wv.y*s.y + wv.z*s.z + wv.w*s.w;
      }
      cls[((size_t)b * NQ + n0 + r0 + r) * 80 + o] = d + ctp_b[o];
    }
  }
}

extern "C" void kernel_launch(void* const* d_in, const int* in_sizes, int n_in,
                              void* d_out, int out_size, void* d_ws, size_t ws_size,
                              hipStream_t stream){
  const float* x      = (const float*)d_in[0];
  const float* ss     = (const float*)d_in[1];
  const float* pos_w  = (const float*)d_in[2];
  const float* pos_b  = (const float*)d_in[3];
  const float* fp_w   = (const float*)d_in[4];
  const float* fp_b   = (const float*)d_in[5];
  const float* bn_g   = (const float*)d_in[6];
  const float* bn_b   = (const float*)d_in[7];
  const float* bn_m   = (const float*)d_in[8];
  const float* bn_v   = (const float*)d_in[9];
  const float* key_w  = (const float*)d_in[10];
  const float* key_b  = (const float*)d_in[11];
  const float* val_w  = (const float*)d_in[12];
  const float* val_b  = (const float*)d_in[13];
  const float* ctp_w  = (const float*)d_in[14];
  const float* ctp_b  = (const float*)d_in[15];
  const float* bb1_w  = (const float*)d_in[16];
  const float* bb1_b  = (const float*)d_in[17];
  const float* bbln_g = (const float*)d_in[18];
  const float* bbln_b = (const float*)d_in[19];
  const float* bb2_w  = (const float*)d_in[20];
  const float* bb2_b  = (const float*)d_in[21];
  const float* bb3_w  = (const float*)d_in[22];
  const float* bb3_b  = (const float*)d_in[23];
  const float* ch1_w  = (const float*)d_in[24];
  const float* ch1_b  = (const float*)d_in[25];
  const float* chln_g = (const float*)d_in[26];
  const float* chln_b = (const float*)d_in[27];
  const float* ch2_w  = (const float*)d_in[28];
  const float* ch2_b  = (const float*)d_in[29];
  const float* ch3_w  = (const float*)d_in[30];
  const float* ch3_b  = (const float*)d_in[31];

  float* out    = (float*)d_out;
  float* boxes  = out + OFF_BOXES;
  float* scores = out + OFF_SCORES;
  float* cls    = out + OFF_CLS;
  float* maps   = out + OFF_MAPS;
  float* divp   = out + OFF_DIV;
  float* sfout  = out + OFF_SF;

  float* ws = (float*)d_ws;
  unsigned short* comb16 = (unsigned short*)(ws + WS_COMB16);
  unsigned short* keys16 = (unsigned short*)(ws + WS_KEYS16);
  unsigned short* attn16 = (unsigned short*)(ws + WS_ATTN16);
  float*          t32    = ws + WS_T32;
  unsigned short* t16    = (unsigned short*)(ws + WS_T16);
  unsigned short* valw16 = (unsigned short*)(ws + WS_VALW16);
  float* sums  = ws + WS_SUMS;
  float* norms = ws + WS_NORM;
  float* dacc  = ws + WS_ACC;
  unsigned short* Pbuf = (unsigned short*)(ws + WS_P);

  bool bigws = ws_size >= WS_TOTAL_P * 4ull;

  zero_kernel<<<1, 1, 0, stream>>>(dacc);
  zero4_kernel<<<1200, 256, 0, stream>>>((float4*)t32, 307200);
  cast_bf16_kernel<<<256, 256, 0, stream>>>(val_w, valw16, 65536);
  pos_fill_kernel<<<2048, 256, 0, stream>>>(pos_w, pos_b, comb16);
  comb_gemm_kernel<<<dim3(32,1,16), dim3(16,16), 0, stream>>>(x, fp_w, fp_b, bn_g, bn_b, bn_m, bn_v, comb16);
  keys_gemm_kernel<<<dim3(32,1,16), dim3(16,16), 0, stream>>>(comb16, key_w, key_b, keys16);

  if (bigws){
    expsum_kernel<<<dim3(NQ/ET, NHH, BB), 256, 0, stream>>>(ss, keys16, Pbuf, sums);
    combine_kernel<<<dim3(NQ/CT, BB), 256, 0, stream>>>(Pbuf, sums, maps, attn16, norms);
  } else {
    attn_kernel<<<dim3(NQ/NT, BB), 256, 0, stream>>>(ss, keys16, maps, attn16, norms);
  }

  // t32 = attn @ comb^T  (split-K x4, fp32 atomic accumulate)
  mfma_nt_splitk_kernel<<<dim3(4,5,BB*4), 64, 0, stream>>>(
      attn16, (size_t)NQ*MM, comb16, (size_t)HIDC*MM,
      t32, (size_t)NQ*HIDC, HIDC, NQ, MM, MM/4);
  cast4_bf16_kernel<<<1200, 256, 0, stream>>>(t32, t16, 307200);
  // sf = t @ val_w^T + val_b  (fp32, straight into d_out)
  mfma_nt_kernel<false><<<dim3(4,5,BB), 64, 0, stream>>>(
      t16, (size_t)NQ*HIDC, valw16, 0, val_b,
      (void*)sfout, (size_t)NQ*HIDC, HIDC, NQ, HIDC);
  simdiv_kernel<<<dim3(16,16), 256, 0, stream>>>(attn16, norms, dacc);
  finalize_kernel<<<1, 1, 0, stream>>>(dacc, divp);
  heads_kernel<<<dim3(15,16), 256, 0, stream>>>(sfout,
      bb1_w, bb1_b, bbln_g, bbln_b, bb2_w, bb2_b, bb3_w, bb3_b,
      ch1_w, ch1_b, chln_g, chln_b, ch2_w, ch2_b, ch3_w, ch3_b,
      ctp_w, ctp_b, boxes, scores, cls);
}

// Round 4
// 577.573 us; speedup vs baseline: 1.7328x; 1.1342x over previous
//
#include <hip/hip_runtime.h>
#include <math.h>

// ---- problem constants ----
#define BB 16
#define CIN 256
#define MM 4096      // H*W
#define HIDC 256
#define NQ 300
#define NHH 4
#define HDD 16

// ---- output offsets (floats) ----
#define OFF_BOXES  0
#define OFF_SCORES 19200
#define OFF_CLS    24000
#define OFF_MAPS   408000
#define OFF_DIV    20068800
#define OFF_SF     20068801

// ---- workspace offsets (in floats) ----
#define WS_COMB16  0            // 16*256*4096 ushort
#define WS_KEYS16  8388608      // 16*64*4096 ushort
#define WS_ATTN16  10485760     // 16*300*4096 ushort
#define WS_T32     20316160     // 16*300*256 fp32
#define WS_T16     21544960     // 16*300*256 ushort
#define WS_VALW16  22159360     // 65536 ushort
#define WS_SUMS    22192128     // 16*4*300 fp32
#define WS_NORM    22211328     // 4800 floats
#define WS_ACC     22216128     // 1 float (+pad)
#define WS_P       22216192     // 16*4*300*4096 ushort = 39321600 floats
#define WS_TOTAL_P 61537792ull  // floats needed for stored-P path

// head scratch aliases the P region (P is dead after combine_kernel).
#define HP_SF16   (WS_P + 0)         // 4800x256 bf16  (614400 fl)
#define HP_Z1PRE  (WS_P + 614400)    // 4800x256 fp32  (1228800 fl)
#define HP_Z1_16  (WS_P + 1843200)   // 4800x256 bf16  (614400 fl)
#define HP_Z2BB   (WS_P + 2457600)   // 4800x128 bf16  (307200 fl)
#define HP_Z2CH   (WS_P + 2764800)   // 4800x128 bf16  (307200 fl)
#define HP_HW     (WS_P + 3072000)   // head weights bf16 (~108.6k fl)
// ushort offsets within HP_HW:
#define HW_BB1 0
#define HW_CH1 65536
#define HW_BB2 131072
#define HW_CH2 163840
#define HW_CTP 196608

typedef short short8 __attribute__((ext_vector_type(8)));
typedef float floatx4 __attribute__((ext_vector_type(4)));

__device__ __forceinline__ unsigned short f2bf(float f){
  unsigned int u = __float_as_uint(f);
  u = (u + 0x7FFFu + ((u >> 16) & 1u)) >> 16;
  return (unsigned short)u;
}
__device__ __forceinline__ float bf1(unsigned short u){
  return __uint_as_float((unsigned int)u << 16);
}
__device__ __forceinline__ float4 ld_bf4(const unsigned short* p){
  ushort4 u = *(const ushort4*)p;
  float4 f;
  f.x = bf1(u.x); f.y = bf1(u.y); f.z = bf1(u.z); f.w = bf1(u.w);
  return f;
}

__global__ void zero_kernel(float* p){ p[0] = 0.f; }

__global__ __launch_bounds__(256) void zero4_kernel(float4* __restrict__ p, int n4){
  int i = blockIdx.x * 256 + threadIdx.x;
  if (i < n4) p[i] = make_float4(0.f, 0.f, 0.f, 0.f);
}

__global__ __launch_bounds__(256) void cast4_bf16_kernel(const float* __restrict__ src,
                                                         unsigned short* __restrict__ dst, int n4){
  int i = blockIdx.x * 256 + threadIdx.x;
  if (i < n4){
    float4 v = ((const float4*)src)[i];
    ushort4 u;
    u.x = f2bf(v.x); u.y = f2bf(v.y); u.z = f2bf(v.z); u.w = f2bf(v.w);
    ((ushort4*)dst)[i] = u;
  }
}

// one fused cast of all bf16 weight copies
__global__ __launch_bounds__(256) void cast_heads_kernel(
    const float* __restrict__ val_w, const float* __restrict__ bb1_w,
    const float* __restrict__ ch1_w, const float* __restrict__ bb2_w,
    const float* __restrict__ ch2_w, const float* __restrict__ ctp_w,
    unsigned short* __restrict__ valw16, unsigned short* __restrict__ hw16){
  int i = blockIdx.x * 256 + threadIdx.x;
  int T = gridDim.x * 256;
  for (int j = i; j < 65536; j += T) valw16[j] = f2bf(val_w[j]);
  for (int j = i; j < 65536; j += T) hw16[HW_BB1 + j] = f2bf(bb1_w[j]);
  for (int j = i; j < 65536; j += T) hw16[HW_CH1 + j] = f2bf(ch1_w[j]);
  for (int j = i; j < 32768; j += T) hw16[HW_BB2 + j] = f2bf(bb2_w[j]);
  for (int j = i; j < 32768; j += T) hw16[HW_CH2 + j] = f2bf(ch2_w[j]);
  for (int j = i; j < 20480; j += T) hw16[HW_CTP + j] = f2bf(ctp_w[j]);
}

// comb rows 128..255 = position encoding (batch-independent, replicated), bf16
__global__ __launch_bounds__(256) void pos_fill_kernel(const float* __restrict__ pos_w,
                                                       const float* __restrict__ pos_b,
                                                       unsigned short* __restrict__ comb16){
  int idx = blockIdx.x * 256 + threadIdx.x;      // c*4096 + m, c in 0..127
  int c = idx >> 12;
  int m = idx & 4095;
  int row = m >> 6, col = m & 63;
  float y = -1.f + 2.f * (float)row / 63.f;
  float x = -1.f + 2.f * (float)col / 63.f;
  unsigned short v = f2bf(pos_w[c*2] * y + pos_w[c*2+1] * x + pos_b[c]);
  #pragma unroll
  for (int b = 0; b < BB; b++)
    comb16[((size_t)(b*HIDC + 128 + c))*MM + m] = v;
}

// comb rows 0..127 = relu(bn(fp_w[0:128] @ x + fp_b)) -> bf16. 128x128 tile, 8x8/thread.
__global__ __launch_bounds__(256) void comb_gemm_kernel(const float* __restrict__ x,
    const float* __restrict__ fp_w, const float* __restrict__ fp_b,
    const float* __restrict__ bn_g, const float* __restrict__ bn_b,
    const float* __restrict__ bn_m, const float* __restrict__ bn_v,
    unsigned short* __restrict__ comb16){
  int b = blockIdx.z;
  int col0 = blockIdx.x * 128;
  const float* xb = x + (size_t)b * CIN * MM;
  unsigned short* cb = comb16 + (size_t)b * HIDC * MM;
  __shared__ float as[16][132];
  __shared__ float bs[16][128];
  int tx = threadIdx.x, ty = threadIdx.y;
  int tid = ty * 16 + tx;
  float acc[8][8] = {};
  for (int k0 = 0; k0 < CIN; k0 += 16){
    {
      int r = tid >> 1, kh = (tid & 1) * 8;
      float4 v0 = *(const float4*)&fp_w[(size_t)r * CIN + k0 + kh];
      float4 v1 = *(const float4*)&fp_w[(size_t)r * CIN + k0 + kh + 4];
      as[kh+0][r] = v0.x; as[kh+1][r] = v0.y; as[kh+2][r] = v0.z; as[kh+3][r] = v0.w;
      as[kh+4][r] = v1.x; as[kh+5][r] = v1.y; as[kh+6][r] = v1.z; as[kh+7][r] = v1.w;
    }
    {
      int kk = tid >> 4, j = (tid & 15) * 8;
      *(float4*)&bs[kk][j]     = *(const float4*)&xb[(size_t)(k0 + kk) * MM + col0 + j];
      *(float4*)&bs[kk][j + 4] = *(const float4*)&xb[(size_t)(k0 + kk) * MM + col0 + j + 4];
    }
    __syncthreads();
    #pragma unroll
    for (int kk = 0; kk < 16; kk++){
      float4 a0 = *(const float4*)&as[kk][ty*8];
      float4 a1 = *(const float4*)&as[kk][ty*8 + 4];
      float4 b0 = *(const float4*)&bs[kk][tx*8];
      float4 b1 = *(const float4*)&bs[kk][tx*8 + 4];
      float av[8] = {a0.x,a0.y,a0.z,a0.w,a1.x,a1.y,a1.z,a1.w};
      float bv[8] = {b0.x,b0.y,b0.z,b0.w,b1.x,b1.y,b1.z,b1.w};
      #pragma unroll
      for (int i = 0; i < 8; i++)
        #pragma unroll
        for (int j = 0; j < 8; j++)
          acc[i][j] += av[i] * bv[j];
    }
    __syncthreads();
  }
  #pragma unroll
  for (int i = 0; i < 8; i++){
    int r = ty*8 + i;
    float sc = rsqrtf(bn_v[r] + 1e-5f);
    float bias = fp_b[r], mu = bn_m[r], g = bn_g[r], bt = bn_b[r];
    ushort4 o0, o1;
    float v;
    v = fmaxf((acc[i][0] + bias - mu) * sc * g + bt, 0.f); o0.x = f2bf(v);
    v = fmaxf((acc[i][1] + bias - mu) * sc * g + bt, 0.f); o0.y = f2bf(v);
    v = fmaxf((acc[i][2] + bias - mu) * sc * g + bt, 0.f); o0.z = f2bf(v);
    v = fmaxf((acc[i][3] + bias - mu) * sc * g + bt, 0.f); o0.w = f2bf(v);
    v = fmaxf((acc[i][4] + bias - mu) * sc * g + bt, 0.f); o1.x = f2bf(v);
    v = fmaxf((acc[i][5] + bias - mu) * sc * g + bt, 0.f); o1.y = f2bf(v);
    v = fmaxf((acc[i][6] + bias - mu) * sc * g + bt, 0.f); o1.z = f2bf(v);
    v = fmaxf((acc[i][7] + bias - mu) * sc * g + bt, 0.f); o1.w = f2bf(v);
    *(ushort4*)&cb[(size_t)r * MM + col0 + tx*8]     = o0;
    *(ushort4*)&cb[(size_t)r * MM + col0 + tx*8 + 4] = o1;
  }
}

// keys = key_w(64x256) @ comb(256x4096) + key_b -> bf16. 64x128 tile, 4x8/thread.
__global__ __launch_bounds__(256) void keys_gemm_kernel(const unsigned short* __restrict__ comb16,
    const float* __restrict__ key_w, const float* __restrict__ key_b,
    unsigned short* __restrict__ keys16){
  int b = blockIdx.z;
  int col0 = blockIdx.x * 128;
  const unsigned short* cb = comb16 + (size_t)b * HIDC * MM;
  unsigned short* kb = keys16 + (size_t)b * 64 * MM;
  __shared__ float as[16][68];
  __shared__ float bs[16][132];
  int tx = threadIdx.x, ty = threadIdx.y;
  int tid = ty * 16 + tx;
  float acc[4][8] = {};
  for (int k0 = 0; k0 < HIDC; k0 += 16){
    {
      int r = tid >> 2, kh = (tid & 3) * 4;
      float4 v0 = *(const float4*)&key_w[(size_t)r * HIDC + k0 + kh];
      as[kh+0][r] = v0.x; as[kh+1][r] = v0.y; as[kh+2][r] = v0.z; as[kh+3][r] = v0.w;
    }
    {
      int kk = tid >> 4, j = (tid & 15) * 8;
      float4 f0 = ld_bf4(&cb[(size_t)(k0 + kk) * MM + col0 + j]);
      float4 f1 = ld_bf4(&cb[(size_t)(k0 + kk) * MM + col0 + j + 4]);
      *(float4*)&bs[kk][j]     = f0;
      *(float4*)&bs[kk][j + 4] = f1;
    }
    __syncthreads();
    #pragma unroll
    for (int kk = 0; kk < 16; kk++){
      float4 a0 = *(const float4*)&as[kk][ty*4];
      float4 b0 = *(const float4*)&bs[kk][tx*8];
      float4 b1 = *(const float4*)&bs[kk][tx*8 + 4];
      float av[4] = {a0.x,a0.y,a0.z,a0.w};
      float bv[8] = {b0.x,b0.y,b0.z,b0.w,b1.x,b1.y,b1.z,b1.w};
      #pragma unroll
      for (int i = 0; i < 4; i++)
        #pragma unroll
        for (int j = 0; j < 8; j++)
          acc[i][j] += av[i] * bv[j];
    }
    __syncthreads();
  }
  #pragma unroll
  for (int i = 0; i < 4; i++){
    int r = ty*4 + i;
    float kbias = key_b[r];
    ushort4 o0, o1;
    o0.x = f2bf(acc[i][0] + kbias); o0.y = f2bf(acc[i][1] + kbias);
    o0.z = f2bf(acc[i][2] + kbias); o0.w = f2bf(acc[i][3] + kbias);
    o1.x = f2bf(acc[i][4] + kbias); o1.y = f2bf(acc[i][5] + kbias);
    o1.z = f2bf(acc[i][6] + kbias); o1.w = f2bf(acc[i][7] + kbias);
    *(ushort4*)&kb[(size_t)r * MM + col0 + tx*8]     = o0;
    *(ushort4*)&kb[(size_t)r * MM + col0 + tx*8 + 4] = o1;
  }
}

// exp(q.k) for 4 consecutive m, accumulated scaled into o
__device__ __forceinline__ void dot16_exp4(const float* qp, const float4* kf, float4& o, float scale){
  float l0 = 0.f, l1 = 0.f, l2 = 0.f, l3 = 0.f;
  #pragma unroll
  for (int d4 = 0; d4 < 4; d4++){
    float4 q = ((const float4*)qp)[d4];
    float4 k0 = kf[d4*4+0], k1 = kf[d4*4+1], k2 = kf[d4*4+2], k3 = kf[d4*4+3];
    l0 += q.x*k0.x + q.y*k1.x + q.z*k2.x + q.w*k3.x;
    l1 += q.x*k0.y + q.y*k1.y + q.z*k2.y + q.w*k3.y;
    l2 += q.x*k0.z + q.y*k1.z + q.z*k2.z + q.w*k3.z;
    l3 += q.x*k0.w + q.y*k1.w + q.z*k2.w + q.w*k3.w;
  }
  o.x += __expf(l0) * scale;
  o.y += __expf(l1) * scale;
  o.z += __expf(l2) * scale;
  o.w += __expf(l3) * scale;
}

// ======== stored-P attention path ========
#define ET 10
__global__ __launch_bounds__(256) void expsum_kernel(const float* __restrict__ ss,
    const unsigned short* __restrict__ keys16,
    unsigned short* __restrict__ P, float* __restrict__ sums){
  int b = blockIdx.z, h = blockIdx.y, n0 = blockIdx.x * ET;
  int tid = threadIdx.x;
  int w = tid >> 6, lane = tid & 63;
  __shared__ float qs[ET][HDD];
  __shared__ float part[NHH][ET];
  if (tid < ET*HDD)
    qs[tid >> 4][tid & 15] = ss[(size_t)(n0 + (tid >> 4))*64 + h*16 + (tid & 15)] * 0.25f;
  __syncthreads();
  const unsigned short* kb = keys16 + ((size_t)b*64 + h*16)*MM;
  unsigned short* Pb = P + (((size_t)b*NHH + h)*NQ + n0)*MM;
  float acc[ET];
  #pragma unroll
  for (int n = 0; n < ET; n++) acc[n] = 0.f;
  for (int it = 0; it < 4; it++){
    int g = it*256 + tid;            // m-group (4 m each)
    float4 kf[16];
    #pragma unroll
    for (int d = 0; d < 16; d++)
      kf[d] = ld_bf4(&kb[(size_t)d*MM + g*4]);
    #pragma unroll
    for (int n = 0; n < ET; n++){
      float4 o = make_float4(0.f,0.f,0.f,0.f);
      dot16_exp4(&qs[n][0], kf, o, 1.f);
      ushort4 u;
      u.x = f2bf(o.x); u.y = f2bf(o.y); u.z = f2bf(o.z); u.w = f2bf(o.w);
      *(ushort4*)&Pb[(size_t)n*MM + g*4] = u;
      acc[n] += o.x + o.y + o.z + o.w;
    }
  }
  #pragma unroll
  for (int n = 0; n < ET; n++){
    float v = acc[n];
    #pragma unroll
    for (int off = 32; off >= 1; off >>= 1) v += __shfl_xor(v, off);
    if (lane == 0) part[w][n] = v;
  }
  __syncthreads();
  if (tid < ET)
    sums[((size_t)b*NHH + h)*NQ + n0 + tid] = part[0][tid] + part[1][tid] + part[2][tid] + part[3][tid];
}

#define CT 3
__global__ __launch_bounds__(256) void combine_kernel(const unsigned short* __restrict__ P,
    const float* __restrict__ sums, float* __restrict__ maps,
    unsigned short* __restrict__ attn16, float* __restrict__ norms){
  int b = blockIdx.y, n0 = blockIdx.x * CT;
  int tid = threadIdx.x;
  int w = tid >> 6, lane = tid & 63;
  __shared__ float inv_s[CT][NHH];
  __shared__ float part[NHH][CT];
  if (tid < CT*NHH){
    int n = tid >> 2, h = tid & 3;
    inv_s[n][h] = 0.25f / sums[((size_t)b*NHH + h)*NQ + n0 + n];
  }
  __syncthreads();
  const unsigned short* Pb = P + ((size_t)b*NHH*NQ + n0)*MM;
  float* mb = maps + ((size_t)b*NQ + n0)*MM;
  unsigned short* ab = attn16 + ((size_t)b*NQ + n0)*MM;
  float nacc[CT];
  #pragma unroll
  for (int n = 0; n < CT; n++) nacc[n] = 0.f;
  for (int it = 0; it < 4; it++){
    int g = it*256 + tid;
    #pragma unroll
    for (int n = 0; n < CT; n++){
      float4 o = make_float4(0.f,0.f,0.f,0.f);
      #pragma unroll
      for (int h = 0; h < NHH; h++){
        float4 p = ld_bf4(&Pb[((size_t)h*NQ + n)*MM + g*4]);
        float iv = inv_s[n][h];
        o.x += p.x*iv; o.y += p.y*iv; o.z += p.z*iv; o.w += p.w*iv;
      }
      *(float4*)&mb[(size_t)n*MM + g*4] = o;
      ushort4 u;
      u.x = f2bf(o.x); u.y = f2bf(o.y); u.z = f2bf(o.z); u.w = f2bf(o.w);
      *(ushort4*)&ab[(size_t)n*MM + g*4] = u;
      nacc[n] += o.x*o.x + o.y*o.y + o.z*o.z + o.w*o.w;
    }
  }
  #pragma unroll
  for (int n = 0; n < CT; n++){
    float v = nacc[n];
    #pragma unroll
    for (int off = 32; off >= 1; off >>= 1) v += __shfl_xor(v, off);
    if (lane == 0) part[w][n] = v;
  }
  __syncthreads();
  if (tid < CT)
    norms[(size_t)b*NQ + n0 + tid] = sqrtf(part[0][tid] + part[1][tid] + part[2][tid] + part[3][tid]);
}

// ======== fallback 2-pass attention (used if ws too small for P) ========
#define NT 10
__global__ __launch_bounds__(256) void attn_kernel(const float* __restrict__ ss,
    const unsigned short* __restrict__ keys16, float* __restrict__ attn_out,
    unsigned short* __restrict__ attn16, float* __restrict__ norms){
  int b = blockIdx.y;
  int n0 = blockIdx.x * NT;
  int tid = threadIdx.x;
  int w = tid >> 6, lane = tid & 63;
  __shared__ float qs[NT][NHH][HDD];
  __shared__ float sums[NT][NHH];
  __shared__ float invs[NT][NHH];
  __shared__ float norms_s[NHH][NT];
  for (int i = tid; i < NT*64; i += 256){
    int n = i >> 6, o = i & 63;
    qs[n][o >> 4][o & 15] = ss[(size_t)(n0 + n)*64 + o] * 0.25f;
  }
  __syncthreads();
  const unsigned short* kb = keys16 + (size_t)b * 64 * MM;
  float acc[NT];
  #pragma unroll
  for (int n = 0; n < NT; n++) acc[n] = 0.f;
  {
    int h = w;
    for (int g = lane; g < 1024; g += 64){
      float4 kf[16];
      #pragma unroll
      for (int d = 0; d < 16; d++)
        kf[d] = ld_bf4(&kb[(size_t)(h*16 + d)*MM + g*4]);
      #pragma unroll
      for (int n = 0; n < NT; n++){
        float4 o = make_float4(0.f,0.f,0.f,0.f);
        dot16_exp4(&qs[n][h][0], kf, o, 1.f);
        acc[n] += o.x + o.y + o.z + o.w;
      }
    }
  }
  #pragma unroll
  for (int n = 0; n < NT; n++){
    float v = acc[n];
    #pragma unroll
    for (int off = 32; off >= 1; off >>= 1) v += __shfl_xor(v, off);
    if (lane == 0) sums[n][w] = v;
  }
  __syncthreads();
  for (int i = tid; i < NT*NHH; i += 256)
    invs[i / NHH][i % NHH] = 0.25f / sums[i / NHH][i % NHH];
  __syncthreads();
  float normacc[NT];
  #pragma unroll
  for (int n = 0; n < NT; n++) normacc[n] = 0.f;
  float* ab = attn_out + ((size_t)b * NQ + n0) * MM;
  unsigned short* ab16 = attn16 + ((size_t)b * NQ + n0) * MM;
  #pragma unroll
  for (int nc = 0; nc < NT; nc += 5){
    for (int g = w*256 + lane; g < (w+1)*256; g += 64){
      float4 o[5];
      #pragma unroll
      for (int j = 0; j < 5; j++) o[j] = make_float4(0.f,0.f,0.f,0.f);
      #pragma unroll
      for (int h = 0; h < 4; h++){
        float4 kf[16];
        #pragma unroll
        for (int d = 0; d < 16; d++)
          kf[d] = ld_bf4(&kb[(size_t)(h*16 + d)*MM + g*4]);
        #pragma unroll
        for (int j = 0; j < 5; j++)
          dot16_exp4(&qs[nc + j][h][0], kf, o[j], invs[nc + j][h]);
      }
      #pragma unroll
      for (int j = 0; j < 5; j++){
        *(float4*)&ab[(size_t)(nc + j)*MM + g*4] = o[j];
        ushort4 u;
        u.x = f2bf(o[j].x); u.y = f2bf(o[j].y); u.z = f2bf(o[j].z); u.w = f2bf(o[j].w);
        *(ushort4*)&ab16[(size_t)(nc + j)*MM + g*4] = u;
        normacc[nc + j] += o[j].x*o[j].x + o[j].y*o[j].y + o[j].z*o[j].z + o[j].w*o[j].w;
      }
    }
  }
  #pragma unroll
  for (int n = 0; n < NT; n++){
    float v = normacc[n];
    #pragma unroll
    for (int off = 32; off >= 1; off >>= 1) v += __shfl_xor(v, off);
    if (lane == 0) norms_s[w][n] = v;
  }
  __syncthreads();
  if (tid < NT){
    float s = norms_s[0][tid] + norms_s[1][tid] + norms_s[2][tid] + norms_s[3][tid];
    norms[(size_t)b * NQ + n0 + tid] = sqrtf(s);
  }
}

// C = A @ B^T (+bias). bf16 NT MFMA, wave per 64x64 tile. Row clamp Mr, col clamp Nc.
// Writes fp32 C (if non-null) and/or bf16 C16 (if non-null); optional fused ReLU.
template<bool RELU>
__global__ __launch_bounds__(64) void mfma_nt_kernel(
    const unsigned short* __restrict__ A, size_t sA,
    const unsigned short* __restrict__ B, size_t sB,
    const float* __restrict__ bias,
    float* __restrict__ C, unsigned short* __restrict__ C16,
    size_t sC, int ldc, int Mr, int Nc, int K){
  int bz = blockIdx.z;
  const unsigned short* Ab = A + (size_t)bz * sA;
  const unsigned short* Bb = B + (size_t)bz * sB;
  int lane = threadIdx.x;
  int r16 = lane & 15;
  int ko  = (lane >> 4) * 8;
  const unsigned short* arow[4];
  const unsigned short* brow[4];
  #pragma unroll
  for (int i = 0; i < 4; i++){
    int m = blockIdx.y*64 + i*16 + r16;
    if (m > Mr - 1) m = Mr - 1;
    arow[i] = Ab + (size_t)m * K + ko;
    int n = blockIdx.x*64 + i*16 + r16;
    if (n > Nc - 1) n = Nc - 1;
    brow[i] = Bb + (size_t)n * K + ko;
  }
  floatx4 acc[4][4];
  #pragma unroll
  for (int i = 0; i < 4; i++)
    #pragma unroll
    for (int j = 0; j < 4; j++)
      acc[i][j] = (floatx4){0.f, 0.f, 0.f, 0.f};
  short8 a[4], bv[4], a2[4], b2[4];
  #pragma unroll
  for (int i = 0; i < 4; i++){
    a[i]  = *(const short8*)(arow[i]);
    bv[i] = *(const short8*)(brow[i]);
  }
  for (int k = 32; k < K; k += 32){
    #pragma unroll
    for (int i = 0; i < 4; i++){
      a2[i] = *(const short8*)(arow[i] + k);
      b2[i] = *(const short8*)(brow[i] + k);
    }
    #pragma unroll
    for (int i = 0; i < 4; i++)
      #pragma unroll
      for (int j = 0; j < 4; j++)
        acc[i][j] = __builtin_amdgcn_mfma_f32_16x16x32_bf16(a[i], bv[j], acc[i][j], 0, 0, 0);
    #pragma unroll
    for (int i = 0; i < 4; i++){ a[i] = a2[i]; bv[i] = b2[i]; }
  }
  #pragma unroll
  for (int i = 0; i < 4; i++)
    #pragma unroll
    for (int j = 0; j < 4; j++)
      acc[i][j] = __builtin_amdgcn_mfma_f32_16x16x32_bf16(a[i], bv[j], acc[i][j], 0, 0, 0);
  int cq = lane & 15, rq = (lane >> 4) * 4;
  #pragma unroll
  for (int j = 0; j < 4; j++){
    int cc = blockIdx.x*64 + j*16 + cq;
    if (cc >= Nc) continue;
    float bv_ = bias ? bias[cc] : 0.f;
    #pragma unroll
    for (int i = 0; i < 4; i++){
      int rbase = blockIdx.y*64 + i*16 + rq;
      #pragma unroll
      for (int reg = 0; reg < 4; reg++){
        int rr = rbase + reg;
        if (rr < Mr){
          float v = acc[i][j][reg] + bv_;
          if (RELU) v = fmaxf(v, 0.f);
          size_t o = (size_t)bz * sC + (size_t)rr * ldc + cc;
          if (C)   C[o] = v;
          if (C16) C16[o] = f2bf(v);
        }
      }
    }
  }
}

// split-K variant: fp32 atomicAdd into pre-zeroed C
__global__ __launch_bounds__(64) void mfma_nt_splitk_kernel(
    const unsigned short* __restrict__ A, size_t sA,
    const unsigned short* __restrict__ B, size_t sB,
    float* __restrict__ C, size_t sC, int ldc, int Mr, int K, int kchunk){
  int nks = K / kchunk;
  int bz = blockIdx.z / nks;
  int kz = blockIdx.z % nks;
  const unsigned short* Ab = A + (size_t)bz * sA + (size_t)kz * kchunk;
  const unsigned short* Bb = B + (size_t)bz * sB + (size_t)kz * kchunk;
  int lane = threadIdx.x;
  int r16 = lane & 15;
  int ko  = (lane >> 4) * 8;
  const unsigned short* arow[4];
  const unsigned short* brow[4];
  #pragma unroll
  for (int i = 0; i < 4; i++){
    int m = blockIdx.y*64 + i*16 + r16;
    if (m > Mr - 1) m = Mr - 1;
    arow[i] = Ab + (size_t)m * K + ko;
    int n = blockIdx.x*64 + i*16 + r16;
    brow[i] = Bb + (size_t)n * K + ko;
  }
  floatx4 acc[4][4];
  #pragma unroll
  for (int i = 0; i < 4; i++)
    #pragma unroll
    for (int j = 0; j < 4; j++)
      acc[i][j] = (floatx4){0.f, 0.f, 0.f, 0.f};
  short8 a[4], bv[4], a2[4], b2[4];
  #pragma unroll
  for (int i = 0; i < 4; i++){
    a[i]  = *(const short8*)(arow[i]);
    bv[i] = *(const short8*)(brow[i]);
  }
  for (int k = 32; k < kchunk; k += 32){
    #pragma unroll
    for (int i = 0; i < 4; i++){
      a2[i] = *(const short8*)(arow[i] + k);
      b2[i] = *(const short8*)(brow[i] + k);
    }
    #pragma unroll
    for (int i = 0; i < 4; i++)
      #pragma unroll
      for (int j = 0; j < 4; j++)
        acc[i][j] = __builtin_amdgcn_mfma_f32_16x16x32_bf16(a[i], bv[j], acc[i][j], 0, 0, 0);
    #pragma unroll
    for (int i = 0; i < 4; i++){ a[i] = a2[i]; bv[i] = b2[i]; }
  }
  #pragma unroll
  for (int i = 0; i < 4; i++)
    #pragma unroll
    for (int j = 0; j < 4; j++)
      acc[i][j] = __builtin_amdgcn_mfma_f32_16x16x32_bf16(a[i], bv[j], acc[i][j], 0, 0, 0);
  int cq = lane & 15, rq = (lane >> 4) * 4;
  #pragma unroll
  for (int j = 0; j < 4; j++){
    int cc = blockIdx.x*64 + j*16 + cq;
    #pragma unroll
    for (int i = 0; i < 4; i++){
      int rbase = blockIdx.y*64 + i*16 + rq;
      #pragma unroll
      for (int reg = 0; reg < 4; reg++){
        int rr = rbase + reg;
        if (rr < Mr)
          atomicAdd(&C[(size_t)bz * sC + (size_t)rr * ldc + cc], acc[i][j][reg]);
      }
    }
  }
}

// LayerNorm + ReLU over 256-wide rows; fp32 in, bf16 out. 4 rows/block (wave per row).
__global__ __launch_bounds__(256) void ln_relu_kernel(const float* __restrict__ zin,
    const float* __restrict__ g, const float* __restrict__ bvec,
    unsigned short* __restrict__ zout){
  int row = blockIdx.x * 4 + (threadIdx.x >> 6);
  int lane = threadIdx.x & 63;
  float4 v = *(const float4*)&zin[(size_t)row * 256 + lane * 4];
  float s = v.x + v.y + v.z + v.w;
  #pragma unroll
  for (int off = 32; off >= 1; off >>= 1) s += __shfl_xor(s, off);
  float mean = s * (1.f/256.f);
  float dx = v.x - mean, dy = v.y - mean, dz = v.z - mean, dw = v.w - mean;
  float sq = dx*dx + dy*dy + dz*dz + dw*dw;
  #pragma unroll
  for (int off = 32; off >= 1; off >>= 1) sq += __shfl_xor(sq, off);
  float inv = rsqrtf(sq * (1.f/256.f) + 1e-5f);
  float4 gv = *(const float4*)&g[lane * 4];
  float4 bb = *(const float4*)&bvec[lane * 4];
  ushort4 u;
  u.x = f2bf(fmaxf(dx*inv*gv.x + bb.x, 0.f));
  u.y = f2bf(fmaxf(dy*inv*gv.y + bb.y, 0.f));
  u.z = f2bf(fmaxf(dz*inv*gv.z + bb.z, 0.f));
  u.w = f2bf(fmaxf(dw*inv*gv.w + bb.w, 0.f));
  *(ushort4*)&zout[(size_t)row * 256 + lane * 4] = u;
}

// final tiny projections: boxes = z2bb @ bb3^T + b; scores = sigmoid(z2ch @ ch3^T + b)
__global__ __launch_bounds__(256) void head3_kernel(
    const unsigned short* __restrict__ z2bb, const unsigned short* __restrict__ z2ch,
    const float* __restrict__ bb3_w, const float* __restrict__ bb3_b,
    const float* __restrict__ ch3_w, const float* __restrict__ ch3_b,
    float* __restrict__ boxes, float* __restrict__ scores){
  int row = blockIdx.x * 4 + (threadIdx.x >> 6);
  int lane = threadIdx.x & 63;
  float zb0 = bf1(z2bb[(size_t)row*128 + 2*lane]);
  float zb1 = bf1(z2bb[(size_t)row*128 + 2*lane + 1]);
  float zc0 = bf1(z2ch[(size_t)row*128 + 2*lane]);
  float zc1 = bf1(z2ch[(size_t)row*128 + 2*lane + 1]);
  float acc[5];
  #pragma unroll
  for (int o = 0; o < 4; o++)
    acc[o] = bb3_w[o*128 + 2*lane]*zb0 + bb3_w[o*128 + 2*lane + 1]*zb1;
  acc[4] = ch3_w[2*lane]*zc0 + ch3_w[2*lane + 1]*zc1;
  #pragma unroll
  for (int o = 0; o < 5; o++){
    float v = acc[o];
    #pragma unroll
    for (int off = 32; off >= 1; off >>= 1) v += __shfl_xor(v, off);
    acc[o] = v;
  }
  if (lane == 0){
    #pragma unroll
    for (int o = 0; o < 4; o++)
      boxes[(size_t)row*4 + o] = acc[o] + bb3_b[o];
    float sv = acc[4] + ch3_b[0];
    scores[row] = 1.f / (1.f + __expf(-sv));
  }
}

// diversity: sum_m (sum_n attn[n,m]/||attn_n||)^2  (bf16 attn copy)
__global__ __launch_bounds__(256) void simdiv_kernel(const unsigned short* __restrict__ attn16,
    const float* __restrict__ norms, float* __restrict__ acc){
  int b = blockIdx.y;
  int m = blockIdx.x * 256 + threadIdx.x;
  __shared__ float inv_s[NQ];
  __shared__ float red[4];
  for (int i = threadIdx.x; i < NQ; i += 256)
    inv_s[i] = 1.f / fmaxf(norms[(size_t)b * NQ + i], 1e-12f);
  __syncthreads();
  const unsigned short* ab = attn16 + (size_t)b * NQ * MM;
  float S = 0.f;
  for (int n = 0; n < NQ; n++)
    S += bf1(ab[(size_t)n * MM + m]) * inv_s[n];
  float p = S * S;
  #pragma unroll
  for (int off = 32; off >= 1; off >>= 1) p += __shfl_xor(p, off);
  int w = threadIdx.x >> 6, lane = threadIdx.x & 63;
  if (lane == 0) red[w] = p;
  __syncthreads();
  if (threadIdx.x == 0) atomicAdd(acc, red[0] + red[1] + red[2] + red[3]);
}

__global__ void finalize_kernel(const float* __restrict__ acc, float* __restrict__ out_div){
  out_div[0] = (acc[0] - (float)(BB * NQ)) / (float)(NQ * (NQ - 1)) * 0.1f;
}

extern "C" void kernel_launch(void* const* d_in, const int* in_sizes, int n_in,
                              void* d_out, int out_size, void* d_ws, size_t ws_size,
                              hipStream_t stream){
  const float* x      = (const float*)d_in[0];
  const float* ss     = (const float*)d_in[1];
  const float* pos_w  = (const float*)d_in[2];
  const float* pos_b  = (const float*)d_in[3];
  const float* fp_w   = (const float*)d_in[4];
  const float* fp_b   = (const float*)d_in[5];
  const float* bn_g   = (const float*)d_in[6];
  const float* bn_b   = (const float*)d_in[7];
  const float* bn_m   = (const float*)d_in[8];
  const float* bn_v   = (const float*)d_in[9];
  const float* key_w  = (const float*)d_in[10];
  const float* key_b  = (const float*)d_in[11];
  const float* val_w  = (const float*)d_in[12];
  const float* val_b  = (const float*)d_in[13];
  const float* ctp_w  = (const float*)d_in[14];
  const float* ctp_b  = (const float*)d_in[15];
  const float* bb1_w  = (const float*)d_in[16];
  const float* bb1_b  = (const float*)d_in[17];
  const float* bbln_g = (const float*)d_in[18];
  const float* bbln_b = (const float*)d_in[19];
  const float* bb2_w  = (const float*)d_in[20];
  const float* bb2_b  = (const float*)d_in[21];
  const float* bb3_w  = (const float*)d_in[22];
  const float* bb3_b  = (const float*)d_in[23];
  const float* ch1_w  = (const float*)d_in[24];
  const float* ch1_b  = (const float*)d_in[25];
  const float* chln_g = (const float*)d_in[26];
  const float* chln_b = (const float*)d_in[27];
  const float* ch2_w  = (const float*)d_in[28];
  const float* ch2_b  = (const float*)d_in[29];
  const float* ch3_w  = (const float*)d_in[30];
  const float* ch3_b  = (const float*)d_in[31];

  float* out    = (float*)d_out;
  float* boxes  = out + OFF_BOXES;
  float* scores = out + OFF_SCORES;
  float* cls    = out + OFF_CLS;
  float* maps   = out + OFF_MAPS;
  float* divp   = out + OFF_DIV;
  float* sfout  = out + OFF_SF;

  float* ws = (float*)d_ws;
  unsigned short* comb16 = (unsigned short*)(ws + WS_COMB16);
  unsigned short* keys16 = (unsigned short*)(ws + WS_KEYS16);
  unsigned short* attn16 = (unsigned short*)(ws + WS_ATTN16);
  float*          t32    = ws + WS_T32;
  unsigned short* t16    = (unsigned short*)(ws + WS_T16);
  unsigned short* valw16 = (unsigned short*)(ws + WS_VALW16);
  float* sums  = ws + WS_SUMS;
  float* norms = ws + WS_NORM;
  float* dacc  = ws + WS_ACC;
  unsigned short* Pbuf = (unsigned short*)(ws + WS_P);
  // head scratch (aliases P region; P dead by the time these are written)
  unsigned short* sf16   = (unsigned short*)(ws + HP_SF16);
  float*          z1pre  = ws + HP_Z1PRE;
  unsigned short* z1_16  = (unsigned short*)(ws + HP_Z1_16);
  unsigned short* z2bb16 = (unsigned short*)(ws + HP_Z2BB);
  unsigned short* z2ch16 = (unsigned short*)(ws + HP_Z2CH);
  unsigned short* hw16   = (unsigned short*)(ws + HP_HW);

  bool bigws = ws_size >= WS_TOTAL_P * 4ull;

  zero_kernel<<<1, 1, 0, stream>>>(dacc);
  zero4_kernel<<<1200, 256, 0, stream>>>((float4*)t32, 307200);
  pos_fill_kernel<<<2048, 256, 0, stream>>>(pos_w, pos_b, comb16);
  comb_gemm_kernel<<<dim3(32,1,16), dim3(16,16), 0, stream>>>(x, fp_w, fp_b, bn_g, bn_b, bn_m, bn_v, comb16);
  keys_gemm_kernel<<<dim3(32,1,16), dim3(16,16), 0, stream>>>(comb16, key_w, key_b, keys16);

  if (bigws){
    expsum_kernel<<<dim3(NQ/ET, NHH, BB), 256, 0, stream>>>(ss, keys16, Pbuf, sums);
    combine_kernel<<<dim3(NQ/CT, BB), 256, 0, stream>>>(Pbuf, sums, maps, attn16, norms);
  } else {
    attn_kernel<<<dim3(NQ/NT, BB), 256, 0, stream>>>(ss, keys16, maps, attn16, norms);
  }

  // t32 = attn @ comb^T  (split-K x4, fp32 atomic accumulate)
  mfma_nt_splitk_kernel<<<dim3(4,5,BB*4), 64, 0, stream>>>(
      attn16, (size_t)NQ*MM, comb16, (size_t)HIDC*MM,
      t32, (size_t)NQ*HIDC, HIDC, NQ, MM, MM/4);
  cast4_bf16_kernel<<<1200, 256, 0, stream>>>(t32, t16, 307200);
  // bf16 weight copies (safe: P region dead after combine)
  cast_heads_kernel<<<256, 256, 0, stream>>>(val_w, bb1_w, ch1_w, bb2_w, ch2_w, ctp_w, valw16, hw16);
  // sf = t @ val_w^T + val_b  (fp32 into d_out, bf16 into sf16)
  mfma_nt_kernel<false><<<dim3(4,5,BB), 64, 0, stream>>>(
      t16, (size_t)NQ*HIDC, valw16, 0, val_b,
      sfout, sf16, (size_t)NQ*HIDC, HIDC, NQ, HIDC, HIDC);

  // ---- boxes head ----
  mfma_nt_kernel<false><<<dim3(4,75,1), 64, 0, stream>>>(
      sf16, 0, hw16 + HW_BB1, 0, bb1_b, z1pre, nullptr, 0, 256, 4800, 256, 256);
  ln_relu_kernel<<<1200, 256, 0, stream>>>(z1pre, bbln_g, bbln_b, z1_16);
  mfma_nt_kernel<true><<<dim3(2,75,1), 64, 0, stream>>>(
      z1_16, 0, hw16 + HW_BB2, 0, bb2_b, nullptr, z2bb16, 0, 128, 4800, 128, 256);
  // ---- scores head ----
  mfma_nt_kernel<false><<<dim3(4,75,1), 64, 0, stream>>>(
      sf16, 0, hw16 + HW_CH1, 0, ch1_b, z1pre, nullptr, 0, 256, 4800, 256, 256);
  ln_relu_kernel<<<1200, 256, 0, stream>>>(z1pre, chln_g, chln_b, z1_16);
  mfma_nt_kernel<true><<<dim3(2,75,1), 64, 0, stream>>>(
      z1_16, 0, hw16 + HW_CH2, 0, ch2_b, nullptr, z2ch16, 0, 128, 4800, 128, 256);
  // ---- finals + cls ----
  head3_kernel<<<1200, 256, 0, stream>>>(z2bb16, z2ch16, bb3_w, bb3_b, ch3_w, ch3_b, boxes, scores);
  mfma_nt_kernel<false><<<dim3(2,75,1), 64, 0, stream>>>(
      sf16, 0, hw16 + HW_CTP, 0, ctp_b, cls, nullptr, 0, 80, 4800, 80, 256);

  simdiv_kernel<<<dim3(16,16), 256, 0, stream>>>(attn16, norms, dacc);
  finalize_kernel<<<1, 1, 0, stream>>>(dacc, divp);
}